// Round 1
// baseline (598.338 us; speedup 1.0000x reference)
//
#include <hip/hip_runtime.h>
#include <hip/hip_bf16.h>

#define B_  2
#define T_  4096
#define C_  768
#define H_  12
#define D_  64
#define BT_ (B_*T_)   // 8192

typedef __attribute__((ext_vector_type(8))) short short8;
typedef __attribute__((ext_vector_type(4))) float f32x4;

__device__ __forceinline__ ushort f2bf(float f) {
  union { __hip_bfloat16 b; ushort u; } cv; cv.b = __float2bfloat16(f); return cv.u;
}
__device__ __forceinline__ float bf2f(ushort u) {
  unsigned x = ((unsigned)u) << 16; float f; __builtin_memcpy(&f, &x, 4); return f;
}

// ---------------- elementwise converts ----------------
__global__ void k_f32_to_bf16(const float* __restrict__ in, ushort* __restrict__ out, int n4) {
  int i = blockIdx.x * blockDim.x + threadIdx.x;
  if (i >= n4) return;
  const float4 v = ((const float4*)in)[i];
  ushort4 o;
  o.x = f2bf(v.x); o.y = f2bf(v.y); o.z = f2bf(v.z); o.w = f2bf(v.w);
  ((ushort4*)out)[i] = o;
}

__global__ void k_rope_tab(float* __restrict__ ctab, float* __restrict__ stab) {
  int i = blockIdx.x * blockDim.x + threadIdx.x;  // T_*32 threads
  int t = i >> 5, p = i & 31;
  float inv = 1.0f / powf(10000.0f, (2.0f * (float)p) / 64.0f);
  float a = (float)t * inv;
  ctab[i] = cosf(a); stab[i] = sinf(a);
}

// in-place RoPE on [B*H, T, 64] bf16; scale folded in (1/8 for q: exact pow2)
__global__ void k_rope_apply(ushort* __restrict__ x, const float* __restrict__ ctab,
                             const float* __restrict__ stab, float scale) {
  int i = blockIdx.x * blockDim.x + threadIdx.x;  // B_*H_*T_*32 threads
  int p = i & 31, t = (i >> 5) & (T_ - 1);
  size_t base = ((size_t)(i >> 5)) * 64 + (size_t)p * 2;
  uint xv = *(const uint*)(x + base);
  float x1 = bf2f((ushort)(xv & 0xffffu)), x2 = bf2f((ushort)(xv >> 16));
  float c = ctab[t * 32 + p], s = stab[t * 32 + p];
  float o1 = (x1 * c - x2 * s) * scale, o2 = (x1 * s + x2 * c) * scale;
  *(uint*)(x + base) = (uint)f2bf(o1) | ((uint)f2bf(o2) << 16);
}

// ---------------- QKV projection GEMM ----------------
// out[m][n] = sum_k xb[m][k] * W[n][k] + bias[n]  (NT layout, both row-major along k)
// 128x128 tile, BK=64, 4 waves each 64x64 (4x4 frags of 16x16x32).
// LDS padded to 72 elems/row (144B stride -> bank-conflict-free ds_read_b128).
__global__ __launch_bounds__(256) void k_qkv_gemm(
    const ushort* __restrict__ xb, const ushort* __restrict__ wq,
    const ushort* __restrict__ wk, const ushort* __restrict__ wv,
    const float* __restrict__ bq, const float* __restrict__ bk, const float* __restrict__ bv,
    ushort* __restrict__ qo, ushort* __restrict__ ko, ushort* __restrict__ vo) {
  __shared__ ushort As[128 * 72];
  __shared__ ushort Bs[128 * 72];
  const int tid = threadIdx.x, l = tid & 63, w = tid >> 6;
  const int lr = l & 15, lg = l >> 4;
  const int m0 = blockIdx.x * 128;
  const int n0g = blockIdx.y * 128;   // 0..2304 (3 projections, 6 tiles each)
  const int proj = n0g / 768;
  const int n0 = n0g % 768;
  const ushort* wsrc = proj == 0 ? wq : (proj == 1 ? wk : wv);
  const int wr = (w >> 1) * 64, wc = (w & 1) * 64;

  f32x4 acc[4][4];
  #pragma unroll
  for (int a = 0; a < 4; ++a)
    #pragma unroll
    for (int b = 0; b < 4; ++b) acc[a][b] = (f32x4){0.f, 0.f, 0.f, 0.f};

  for (int k0 = 0; k0 < 768; k0 += 64) {
    #pragma unroll
    for (int i = 0; i < 4; ++i) {
      int seg = tid + i * 256;            // 1024 segments of 8 bf16
      int row = seg >> 3, c8 = (seg & 7) << 3;
      *(short8*)&As[row * 72 + c8] = *(const short8*)(xb + (size_t)(m0 + row) * 768 + k0 + c8);
      *(short8*)&Bs[row * 72 + c8] = *(const short8*)(wsrc + (size_t)(n0 + row) * 768 + k0 + c8);
    }
    __syncthreads();
    #pragma unroll
    for (int kk = 0; kk < 2; ++kk) {
      short8 af[4], bf[4];
      #pragma unroll
      for (int mi = 0; mi < 4; ++mi)
        af[mi] = *(const short8*)&As[(wr + mi * 16 + lr) * 72 + kk * 32 + lg * 8];
      #pragma unroll
      for (int ni = 0; ni < 4; ++ni)
        bf[ni] = *(const short8*)&Bs[(wc + ni * 16 + lr) * 72 + kk * 32 + lg * 8];
      #pragma unroll
      for (int mi = 0; mi < 4; ++mi)
        #pragma unroll
        for (int ni = 0; ni < 4; ++ni)
          acc[mi][ni] = __builtin_amdgcn_mfma_f32_16x16x32_bf16(af[mi], bf[ni], acc[mi][ni], 0, 0, 0);
    }
    __syncthreads();
  }

  const float* bias = proj == 0 ? bq : (proj == 1 ? bk : bv);
  ushort* dst = proj == 0 ? qo : (proj == 1 ? ko : vo);
  // C frag layout: col = lane&15, row = (lane>>4)*4 + j  [verified m89/m91]
  #pragma unroll
  for (int mi = 0; mi < 4; ++mi) {
    #pragma unroll
    for (int ni = 0; ni < 4; ++ni) {
      int colc = n0 + wc + ni * 16 + lr;     // 0..767
      float bb = bias[colc];
      int h = colc >> 6, d = colc & 63;
      #pragma unroll
      for (int j = 0; j < 4; ++j) {
        int row = m0 + wr + mi * 16 + lg * 4 + j;     // 0..8191
        int b = row >> 12, t = row & (T_ - 1);
        dst[((((size_t)b * H_ + h) << 12) + t) * 64 + d] = f2bf(acc[mi][ni][j] + bb);
      }
    }
  }
}

// ---------------- output projection GEMM (f32 out) ----------------
__global__ __launch_bounds__(256) void k_proj_gemm(
    const ushort* __restrict__ yb, const ushort* __restrict__ wp,
    const float* __restrict__ bp, float* __restrict__ out) {
  __shared__ ushort As[128 * 72];
  __shared__ ushort Bs[128 * 72];
  const int tid = threadIdx.x, l = tid & 63, w = tid >> 6;
  const int lr = l & 15, lg = l >> 4;
  const int m0 = blockIdx.x * 128;
  const int n0 = blockIdx.y * 128;
  const int wr = (w >> 1) * 64, wc = (w & 1) * 64;

  f32x4 acc[4][4];
  #pragma unroll
  for (int a = 0; a < 4; ++a)
    #pragma unroll
    for (int b = 0; b < 4; ++b) acc[a][b] = (f32x4){0.f, 0.f, 0.f, 0.f};

  for (int k0 = 0; k0 < 768; k0 += 64) {
    #pragma unroll
    for (int i = 0; i < 4; ++i) {
      int seg = tid + i * 256;
      int row = seg >> 3, c8 = (seg & 7) << 3;
      *(short8*)&As[row * 72 + c8] = *(const short8*)(yb + (size_t)(m0 + row) * 768 + k0 + c8);
      *(short8*)&Bs[row * 72 + c8] = *(const short8*)(wp + (size_t)(n0 + row) * 768 + k0 + c8);
    }
    __syncthreads();
    #pragma unroll
    for (int kk = 0; kk < 2; ++kk) {
      short8 af[4], bf[4];
      #pragma unroll
      for (int mi = 0; mi < 4; ++mi)
        af[mi] = *(const short8*)&As[(wr + mi * 16 + lr) * 72 + kk * 32 + lg * 8];
      #pragma unroll
      for (int ni = 0; ni < 4; ++ni)
        bf[ni] = *(const short8*)&Bs[(wc + ni * 16 + lr) * 72 + kk * 32 + lg * 8];
      #pragma unroll
      for (int mi = 0; mi < 4; ++mi)
        #pragma unroll
        for (int ni = 0; ni < 4; ++ni)
          acc[mi][ni] = __builtin_amdgcn_mfma_f32_16x16x32_bf16(af[mi], bf[ni], acc[mi][ni], 0, 0, 0);
    }
    __syncthreads();
  }

  #pragma unroll
  for (int mi = 0; mi < 4; ++mi)
    #pragma unroll
    for (int ni = 0; ni < 4; ++ni) {
      int col = n0 + wc + ni * 16 + lr;
      float bb = bp[col];
      #pragma unroll
      for (int j = 0; j < 4; ++j) {
        int row = m0 + wr + mi * 16 + lg * 4 + j;
        out[(size_t)row * 768 + col] = acc[mi][ni][j] + bb;
      }
    }
}

// ---------------- causal flash attention ----------------
// grid (T/64, B*H), 4 waves; wave w owns q-rows [qt*64+w*16, +16). KBLK=64.
// q,k,v: [B*H, T, 64] bf16 (q pre-scaled by 1/8). y out: [B, T, C] bf16.
__global__ __launch_bounds__(256) void k_attn(
    const ushort* __restrict__ q, const ushort* __restrict__ k,
    const ushort* __restrict__ v, ushort* __restrict__ y) {
  __shared__ ushort Ks[64 * 72];       // K rows (key-major)
  __shared__ ushort Vs[64 * 72];       // V transposed: Vs[d][key]
  __shared__ ushort Ps[4][16 * 72];    // per-wave P relayout buffer
  const int tid = threadIdx.x, l = tid & 63, w = tid >> 6;
  const int lr = l & 15, lg = l >> 4;
  const int qt = blockIdx.x, bh = blockIdx.y;
  const size_t plane = (size_t)bh * T_ * 64;

  // Q fragments (A operand: row = lane&15, k = (lane>>4)*8+i, kk in {0,32})
  short8 qf[2];
  const int qrow = qt * 64 + w * 16 + lr;
  #pragma unroll
  for (int kk = 0; kk < 2; ++kk)
    qf[kk] = *(const short8*)(q + plane + (size_t)qrow * 64 + kk * 32 + lg * 8);

  f32x4 o[4];
  float m[4], lsum[4];
  #pragma unroll
  for (int c = 0; c < 4; ++c) o[c] = (f32x4){0.f, 0.f, 0.f, 0.f};
  #pragma unroll
  for (int j = 0; j < 4; ++j) { m[j] = -1e30f; lsum[j] = 0.f; }

  for (int kt = 0; kt <= qt; ++kt) {
    // stage K row-major, V transposed
    #pragma unroll
    for (int i = 0; i < 2; ++i) {
      int seg = tid + i * 256;           // 512 segments of 8
      int row = seg >> 3, c8 = (seg & 7) << 3;
      *(short8*)&Ks[row * 72 + c8] = *(const short8*)(k + plane + (size_t)(kt * 64 + row) * 64 + c8);
      short8 vv = *(const short8*)(v + plane + (size_t)(kt * 64 + row) * 64 + c8);
      #pragma unroll
      for (int e = 0; e < 8; ++e) Vs[(c8 + e) * 72 + row] = (ushort)vv[e];
    }
    __syncthreads();

    // S = Q*K^T (scale already folded into q)
    f32x4 s[4];
    #pragma unroll
    for (int c = 0; c < 4; ++c) {
      s[c] = (f32x4){0.f, 0.f, 0.f, 0.f};
      #pragma unroll
      for (int kk = 0; kk < 2; ++kk) {
        short8 kf = *(const short8*)&Ks[(c * 16 + lr) * 72 + kk * 32 + lg * 8];
        s[c] = __builtin_amdgcn_mfma_f32_16x16x32_bf16(qf[kk], kf, s[c], 0, 0, 0);
      }
    }

    if (kt == qt) {   // causal mask, diagonal tile only
      #pragma unroll
      for (int c = 0; c < 4; ++c)
        #pragma unroll
        for (int j = 0; j < 4; ++j)
          if (c * 16 + lr > w * 16 + lg * 4 + j) s[c][j] = -1e30f;
    }

    // online softmax: row r of S frag = (lane>>4)*4 + j, col = c*16 + (lane&15)
    float corr[4], rsum[4];
    #pragma unroll
    for (int j = 0; j < 4; ++j) {
      float rm = fmaxf(fmaxf(s[0][j], s[1][j]), fmaxf(s[2][j], s[3][j]));
      #pragma unroll
      for (int off = 1; off < 16; off <<= 1)
        rm = fmaxf(rm, __shfl_xor(rm, off));
      float mn = fmaxf(m[j], rm);
      corr[j] = expf(m[j] - mn);
      m[j] = mn;
      rsum[j] = 0.f;
    }
    #pragma unroll
    for (int c = 0; c < 4; ++c)
      #pragma unroll
      for (int j = 0; j < 4; ++j) {
        float p = expf(s[c][j] - m[j]);
        rsum[j] += p;
        Ps[w][(lg * 4 + j) * 72 + c * 16 + lr] = f2bf(p);
      }
    #pragma unroll
    for (int j = 0; j < 4; ++j) {
      #pragma unroll
      for (int off = 1; off < 16; off <<= 1)
        rsum[j] += __shfl_xor(rsum[j], off);
      lsum[j] = lsum[j] * corr[j] + rsum[j];
    }
    #pragma unroll
    for (int c = 0; c < 4; ++c)
      #pragma unroll
      for (int j = 0; j < 4; ++j) o[c][j] *= corr[j];

    // PV: A = P (re-read in A layout from LDS), B = V^T staged as Vs[d][key]
    short8 pf[2];
    #pragma unroll
    for (int kk = 0; kk < 2; ++kk)
      pf[kk] = *(const short8*)&Ps[w][lr * 72 + kk * 32 + lg * 8];
    #pragma unroll
    for (int c = 0; c < 4; ++c) {
      #pragma unroll
      for (int kk = 0; kk < 2; ++kk) {
        short8 vf = *(const short8*)&Vs[(c * 16 + lr) * 72 + kk * 32 + lg * 8];
        o[c] = __builtin_amdgcn_mfma_f32_16x16x32_bf16(pf[kk], vf, o[c], 0, 0, 0);
      }
    }
    __syncthreads();
  }

  // normalize + write y in [B, T, H*64] layout for the output projection
  const int b = bh / H_, h = bh % H_;
  #pragma unroll
  for (int c = 0; c < 4; ++c)
    #pragma unroll
    for (int j = 0; j < 4; ++j) {
      int row = qt * 64 + w * 16 + lg * 4 + j;
      float val = o[c][j] / lsum[j];
      y[((size_t)b * T_ + row) * C_ + h * 64 + c * 16 + lr] = f2bf(val);
    }
}

extern "C" void kernel_launch(void* const* d_in, const int* in_sizes, int n_in,
                              void* d_out, int out_size, void* d_ws, size_t ws_size,
                              hipStream_t stream) {
  const float* x  = (const float*)d_in[0];
  const float* Wq = (const float*)d_in[1];
  const float* bq = (const float*)d_in[2];
  const float* Wk = (const float*)d_in[3];
  const float* bk = (const float*)d_in[4];
  const float* Wv = (const float*)d_in[5];
  const float* bv = (const float*)d_in[6];
  const float* Wp = (const float*)d_in[7];
  const float* bp = (const float*)d_in[8];
  float* out = (float*)d_out;

  char* p = (char*)d_ws;
  auto alloc = [&](size_t bytes) { char* r = p; p += (bytes + 255) & ~255ULL; return r; };
  ushort* xb  = (ushort*)alloc((size_t)BT_ * C_ * 2);
  ushort* wqb = (ushort*)alloc((size_t)C_ * C_ * 2);
  ushort* wkb = (ushort*)alloc((size_t)C_ * C_ * 2);
  ushort* wvb = (ushort*)alloc((size_t)C_ * C_ * 2);
  ushort* wpb = (ushort*)alloc((size_t)C_ * C_ * 2);
  ushort* qb  = (ushort*)alloc((size_t)BT_ * C_ * 2);
  ushort* kb  = (ushort*)alloc((size_t)BT_ * C_ * 2);
  ushort* vb  = (ushort*)alloc((size_t)BT_ * C_ * 2);
  ushort* yb  = (ushort*)alloc((size_t)BT_ * C_ * 2);
  float* ctab = (float*)alloc((size_t)T_ * 32 * 4);
  float* stab = (float*)alloc((size_t)T_ * 32 * 4);

  k_f32_to_bf16<<<(BT_ * C_ / 4 + 255) / 256, 256, 0, stream>>>(x, xb, BT_ * C_ / 4);
  k_f32_to_bf16<<<(C_ * C_ / 4 + 255) / 256, 256, 0, stream>>>(Wq, wqb, C_ * C_ / 4);
  k_f32_to_bf16<<<(C_ * C_ / 4 + 255) / 256, 256, 0, stream>>>(Wk, wkb, C_ * C_ / 4);
  k_f32_to_bf16<<<(C_ * C_ / 4 + 255) / 256, 256, 0, stream>>>(Wv, wvb, C_ * C_ / 4);
  k_f32_to_bf16<<<(C_ * C_ / 4 + 255) / 256, 256, 0, stream>>>(Wp, wpb, C_ * C_ / 4);
  k_rope_tab<<<T_ * 32 / 256, 256, 0, stream>>>(ctab, stab);

  k_qkv_gemm<<<dim3(BT_ / 128, 2304 / 128), 256, 0, stream>>>(
      xb, wqb, wkb, wvb, bq, bk, bv, qb, kb, vb);

  k_rope_apply<<<(B_ * H_ * T_ * 32) / 256, 256, 0, stream>>>(qb, ctab, stab, 0.125f);
  k_rope_apply<<<(B_ * H_ * T_ * 32) / 256, 256, 0, stream>>>(kb, ctab, stab, 1.0f);

  k_attn<<<dim3(T_ / 64, B_ * H_), 256, 0, stream>>>(qb, kb, vb, yb);

  k_proj_gemm<<<dim3(BT_ / 128, C_ / 128), 256, 0, stream>>>(yb, wpb, bp, out);
}

// Round 2
// 426.099 us; speedup vs baseline: 1.4042x; 1.4042x over previous
//
#include <hip/hip_runtime.h>
#include <hip/hip_bf16.h>

#define B_  2
#define T_  4096
#define C_  768
#define H_  12
#define D_  64
#define BT_ (B_*T_)   // 8192

typedef __attribute__((ext_vector_type(8))) short short8;
typedef __attribute__((ext_vector_type(4))) float f32x4;

union U32x4 { short8 s8; unsigned u[4]; };

__device__ __forceinline__ ushort f2bf(float f) {
  union { __hip_bfloat16 b; ushort u; } cv; cv.b = __float2bfloat16(f); return cv.u;
}
__device__ __forceinline__ float bf2f(ushort u) {
  unsigned x = ((unsigned)u) << 16; float f; __builtin_memcpy(&f, &x, 4); return f;
}
__device__ __forceinline__ unsigned pack2(float a, float b) {
  return (unsigned)f2bf(a) | ((unsigned)f2bf(b) << 16);
}

// ---------------- elementwise converts ----------------
__global__ void k_f32_to_bf16(const float* __restrict__ in, ushort* __restrict__ out, int n4) {
  int i = blockIdx.x * blockDim.x + threadIdx.x;
  if (i >= n4) return;
  const float4 v = ((const float4*)in)[i];
  ushort4 o;
  o.x = f2bf(v.x); o.y = f2bf(v.y); o.z = f2bf(v.z); o.w = f2bf(v.w);
  ((ushort4*)out)[i] = o;
}

__global__ void k_rope_tab(float* __restrict__ ctab, float* __restrict__ stab) {
  int i = blockIdx.x * blockDim.x + threadIdx.x;  // T_*32 threads
  int t = i >> 5, p = i & 31;
  float inv = 1.0f / powf(10000.0f, (2.0f * (float)p) / 64.0f);
  float a = (float)t * inv;
  ctab[i] = cosf(a); stab[i] = sinf(a);
}

// in-place RoPE on [B*H, T, 64] bf16; q gets 1/8*log2(e) folded (exp2-domain softmax)
__global__ void k_rope_apply(ushort* __restrict__ x, const float* __restrict__ ctab,
                             const float* __restrict__ stab, float scale) {
  int i = blockIdx.x * blockDim.x + threadIdx.x;  // B_*H_*T_*32 threads
  int p = i & 31, t = (i >> 5) & (T_ - 1);
  size_t base = ((size_t)(i >> 5)) * 64 + (size_t)p * 2;
  uint xv = *(const uint*)(x + base);
  float x1 = bf2f((ushort)(xv & 0xffffu)), x2 = bf2f((ushort)(xv >> 16));
  float c = ctab[t * 32 + p], s = stab[t * 32 + p];
  float o1 = (x1 * c - x2 * s) * scale, o2 = (x1 * s + x2 * c) * scale;
  *(uint*)(x + base) = (uint)f2bf(o1) | ((uint)f2bf(o2) << 16);
}

// ---------------- QKV projection GEMM ----------------
// q,k -> [B,H,T,64]; v -> TRANSPOSED [B,H,64,T] (attn consumes V^T fragments).
__global__ __launch_bounds__(256) void k_qkv_gemm(
    const ushort* __restrict__ xb, const ushort* __restrict__ wq,
    const ushort* __restrict__ wk, const ushort* __restrict__ wv,
    const float* __restrict__ bq, const float* __restrict__ bk, const float* __restrict__ bv,
    ushort* __restrict__ qo, ushort* __restrict__ ko, ushort* __restrict__ vo) {
  __shared__ __align__(16) ushort As[128 * 72];
  __shared__ __align__(16) ushort Bs[128 * 72];
  const int tid = threadIdx.x, l = tid & 63, w = tid >> 6;
  const int lr = l & 15, lg = l >> 4;
  const int m0 = blockIdx.x * 128;
  const int n0g = blockIdx.y * 128;
  const int proj = n0g / 768;
  const int n0 = n0g % 768;
  const ushort* wsrc = proj == 0 ? wq : (proj == 1 ? wk : wv);
  const int wr = (w >> 1) * 64, wc = (w & 1) * 64;

  f32x4 acc[4][4];
  #pragma unroll
  for (int a = 0; a < 4; ++a)
    #pragma unroll
    for (int b = 0; b < 4; ++b) acc[a][b] = (f32x4){0.f, 0.f, 0.f, 0.f};

  for (int k0 = 0; k0 < 768; k0 += 64) {
    #pragma unroll
    for (int i = 0; i < 4; ++i) {
      int seg = tid + i * 256;
      int row = seg >> 3, c8 = (seg & 7) << 3;
      *(short8*)&As[row * 72 + c8] = *(const short8*)(xb + (size_t)(m0 + row) * 768 + k0 + c8);
      *(short8*)&Bs[row * 72 + c8] = *(const short8*)(wsrc + (size_t)(n0 + row) * 768 + k0 + c8);
    }
    __syncthreads();
    #pragma unroll
    for (int kk = 0; kk < 2; ++kk) {
      short8 af[4], bf[4];
      #pragma unroll
      for (int mi = 0; mi < 4; ++mi)
        af[mi] = *(const short8*)&As[(wr + mi * 16 + lr) * 72 + kk * 32 + lg * 8];
      #pragma unroll
      for (int ni = 0; ni < 4; ++ni)
        bf[ni] = *(const short8*)&Bs[(wc + ni * 16 + lr) * 72 + kk * 32 + lg * 8];
      #pragma unroll
      for (int mi = 0; mi < 4; ++mi)
        #pragma unroll
        for (int ni = 0; ni < 4; ++ni)
          acc[mi][ni] = __builtin_amdgcn_mfma_f32_16x16x32_bf16(af[mi], bf[ni], acc[mi][ni], 0, 0, 0);
    }
    __syncthreads();
  }

  const float* bias = proj == 0 ? bq : (proj == 1 ? bk : bv);
  if (proj == 2) {
    // V^T epilogue: vo[((b*H+h)*64 + d)*T + t], 4 consecutive t per lane (j-quad)
    #pragma unroll
    for (int mi = 0; mi < 4; ++mi) {
      #pragma unroll
      for (int ni = 0; ni < 4; ++ni) {
        int colc = n0 + wc + ni * 16 + lr;
        float bb = bias[colc];
        int h = colc >> 6, d = colc & 63;
        int row0 = m0 + wr + mi * 16 + lg * 4;
        int b = row0 >> 12, t0 = row0 & (T_ - 1);
        ushort4 pk;
        pk.x = f2bf(acc[mi][ni][0] + bb);
        pk.y = f2bf(acc[mi][ni][1] + bb);
        pk.z = f2bf(acc[mi][ni][2] + bb);
        pk.w = f2bf(acc[mi][ni][3] + bb);
        *(ushort4*)(vo + (((size_t)b * H_ + h) * 64 + d) * T_ + t0) = pk;
      }
    }
  } else {
    ushort* dst = proj == 0 ? qo : ko;
    #pragma unroll
    for (int mi = 0; mi < 4; ++mi) {
      #pragma unroll
      for (int ni = 0; ni < 4; ++ni) {
        int colc = n0 + wc + ni * 16 + lr;
        float bb = bias[colc];
        int h = colc >> 6, d = colc & 63;
        #pragma unroll
        for (int j = 0; j < 4; ++j) {
          int row = m0 + wr + mi * 16 + lg * 4 + j;
          int b = row >> 12, t = row & (T_ - 1);
          dst[((((size_t)b * H_ + h) << 12) + t) * 64 + d] = f2bf(acc[mi][ni][j] + bb);
        }
      }
    }
  }
}

// ---------------- output projection GEMM (f32 out) ----------------
__global__ __launch_bounds__(256) void k_proj_gemm(
    const ushort* __restrict__ yb, const ushort* __restrict__ wp,
    const float* __restrict__ bp, float* __restrict__ out) {
  __shared__ __align__(16) ushort As[128 * 72];
  __shared__ __align__(16) ushort Bs[128 * 72];
  const int tid = threadIdx.x, l = tid & 63, w = tid >> 6;
  const int lr = l & 15, lg = l >> 4;
  const int m0 = blockIdx.x * 128;
  const int n0 = blockIdx.y * 128;
  const int wr = (w >> 1) * 64, wc = (w & 1) * 64;

  f32x4 acc[4][4];
  #pragma unroll
  for (int a = 0; a < 4; ++a)
    #pragma unroll
    for (int b = 0; b < 4; ++b) acc[a][b] = (f32x4){0.f, 0.f, 0.f, 0.f};

  for (int k0 = 0; k0 < 768; k0 += 64) {
    #pragma unroll
    for (int i = 0; i < 4; ++i) {
      int seg = tid + i * 256;
      int row = seg >> 3, c8 = (seg & 7) << 3;
      *(short8*)&As[row * 72 + c8] = *(const short8*)(yb + (size_t)(m0 + row) * 768 + k0 + c8);
      *(short8*)&Bs[row * 72 + c8] = *(const short8*)(wp + (size_t)(n0 + row) * 768 + k0 + c8);
    }
    __syncthreads();
    #pragma unroll
    for (int kk = 0; kk < 2; ++kk) {
      short8 af[4], bf[4];
      #pragma unroll
      for (int mi = 0; mi < 4; ++mi)
        af[mi] = *(const short8*)&As[(wr + mi * 16 + lr) * 72 + kk * 32 + lg * 8];
      #pragma unroll
      for (int ni = 0; ni < 4; ++ni)
        bf[ni] = *(const short8*)&Bs[(wc + ni * 16 + lr) * 72 + kk * 32 + lg * 8];
      #pragma unroll
      for (int mi = 0; mi < 4; ++mi)
        #pragma unroll
        for (int ni = 0; ni < 4; ++ni)
          acc[mi][ni] = __builtin_amdgcn_mfma_f32_16x16x32_bf16(af[mi], bf[ni], acc[mi][ni], 0, 0, 0);
    }
    __syncthreads();
  }

  #pragma unroll
  for (int mi = 0; mi < 4; ++mi)
    #pragma unroll
    for (int ni = 0; ni < 4; ++ni) {
      int col = n0 + wc + ni * 16 + lr;
      float bb = bp[col];
      #pragma unroll
      for (int j = 0; j < 4; ++j) {
        int row = m0 + wr + mi * 16 + lg * 4 + j;
        out[(size_t)row * 768 + col] = acc[mi][ni][j] + bb;
      }
    }
}

// ---------------- causal flash attention (swapped-QK^T, in-register softmax) ----
// grid (T/128, B*H) with REVERSED qb order; 4 waves, wave w owns q rows
// [qb*128 + w*32, +32) as 2 M-frags. KBLK=64, double-buffered XOR-swizzled LDS.
// q pre-scaled by log2(e)/8 -> softmax in exp2 domain.
__global__ __launch_bounds__(256) void k_attn(
    const ushort* __restrict__ q, const ushort* __restrict__ k,
    const ushort* __restrict__ vt, ushort* __restrict__ y) {
  __shared__ __align__(16) ushort Ks[2][64 * 64];
  __shared__ __align__(16) ushort Vs[2][64 * 64];
  const int tid = threadIdx.x, l = tid & 63, w = tid >> 6;
  const int lr = l & 15, lg = l >> 4;
  const int qb = (int)gridDim.x - 1 - (int)blockIdx.x;   // big blocks launch first
  const int bh = blockIdx.y;
  const size_t kpl = (size_t)bh * T_ * 64;
  const size_t vpl = (size_t)bh * 64 * T_;
  const int qbase = qb * 128 + w * 32;

  // Q fragments (B operand of S^T = K·Q: col=q=lane&15, k = d)
  short8 qf[2][2];
  #pragma unroll
  for (int mi = 0; mi < 2; ++mi)
    #pragma unroll
    for (int kk = 0; kk < 2; ++kk)
      qf[mi][kk] = *(const short8*)(q + kpl + (size_t)(qbase + mi * 16 + lr) * 64 + kk * 32 + lg * 8);

  f32x4 o[2][4];
  float mx[2], ls[2];
  #pragma unroll
  for (int mi = 0; mi < 2; ++mi) {
    mx[mi] = -1e30f; ls[mi] = 0.f;
    #pragma unroll
    for (int c = 0; c < 4; ++c) o[mi][c] = (f32x4){0.f, 0.f, 0.f, 0.f};
  }

  const int nt = 2 * qb + 2;
  // prologue: stage tile 0 into buf 0 (XOR-swizzled 16B slots)
  {
    #pragma unroll
    for (int i = 0; i < 2; ++i) {
      int r = w * 16 + i * 8 + (l >> 3);
      int sl = (l & 7) ^ (r & 7);
      short8 sk = *(const short8*)(k + kpl + (size_t)r * 64 + (l & 7) * 8);
      short8 sv = *(const short8*)(vt + vpl + (size_t)r * T_ + (l & 7) * 8);
      *(short8*)&Ks[0][r * 64 + sl * 8] = sk;
      *(short8*)&Vs[0][r * 64 + sl * 8] = sv;
    }
  }

  int buf = 0;
  for (int kt = 0; kt < nt; ++kt) {
    __syncthreads();
    // async-split staging: issue next tile's global loads before compute
    short8 sk[2], sv[2];
    const bool pre = (kt + 1 < nt);
    if (pre) {
      #pragma unroll
      for (int i = 0; i < 2; ++i) {
        int r = w * 16 + i * 8 + (l >> 3);
        sk[i] = *(const short8*)(k + kpl + (size_t)((kt + 1) * 64 + r) * 64 + (l & 7) * 8);
        sv[i] = *(const short8*)(vt + vpl + (size_t)r * T_ + (kt + 1) * 64 + (l & 7) * 8);
      }
    }

    const bool active = (kt * 64 <= qbase + 31);
    if (active) {
      // ---- S^T = K·Q ----
      f32x4 sT[2][4];
      #pragma unroll
      for (int c = 0; c < 4; ++c) {
        short8 kf0 = *(const short8*)&Ks[buf][(c * 16 + lr) * 64 + ((lg) ^ (lr & 7)) * 8];
        short8 kf1 = *(const short8*)&Ks[buf][(c * 16 + lr) * 64 + ((4 + lg) ^ (lr & 7)) * 8];
        #pragma unroll
        for (int mi = 0; mi < 2; ++mi) {
          f32x4 z = (f32x4){0.f, 0.f, 0.f, 0.f};
          z = __builtin_amdgcn_mfma_f32_16x16x32_bf16(kf0, qf[mi][0], z, 0, 0, 0);
          z = __builtin_amdgcn_mfma_f32_16x16x32_bf16(kf1, qf[mi][1], z, 0, 0, 0);
          sT[mi][c] = z;
        }
      }

      U32x4 pa[2][2];
      float corr[2];
      #pragma unroll
      for (int mi = 0; mi < 2; ++mi) {
        // causal mask (S^T: row=key=c*16+lg*4+j, col=q=lr)
        if (kt * 64 + 63 > qbase + mi * 16) {
          int qg = qbase + mi * 16 + lr;
          #pragma unroll
          for (int c = 0; c < 4; ++c)
            #pragma unroll
            for (int j = 0; j < 4; ++j)
              if (kt * 64 + c * 16 + lg * 4 + j > qg) sT[mi][c][j] = -1e30f;
        }
        // in-lane + 2-shfl row reduce (full row of 64 keys per q)
        float vmax = sT[mi][0][0];
        #pragma unroll
        for (int c = 0; c < 4; ++c)
          #pragma unroll
          for (int j = 0; j < 4; ++j) vmax = fmaxf(vmax, sT[mi][c][j]);
        vmax = fmaxf(vmax, __shfl_xor(vmax, 16));
        vmax = fmaxf(vmax, __shfl_xor(vmax, 32));
        float mn = fmaxf(mx[mi], vmax);
        corr[mi] = exp2f(mx[mi] - mn);
        mx[mi] = mn;
        float p[4][4], rs = 0.f;
        #pragma unroll
        for (int c = 0; c < 4; ++c)
          #pragma unroll
          for (int j = 0; j < 4; ++j) {
            p[c][j] = exp2f(sT[mi][c][j] - mn);
            rs += p[c][j];
          }
        rs += __shfl_xor(rs, 16);
        rs += __shfl_xor(rs, 32);
        ls[mi] = ls[mi] * corr[mi] + rs;

        // pack P to bf16 pairs: q32[c][u] = keys {c*16+lg*4+2u, +1}
        unsigned q32[4][2];
        #pragma unroll
        for (int c = 0; c < 4; ++c) {
          q32[c][0] = pack2(p[c][0], p[c][1]);
          q32[c][1] = pack2(p[c][2], p[c][3]);
        }
        // exchange into PV A-frag: word(lg_t,kk,w) = q32[2kk+(lg_t>>1)][w&1]
        // from lane lr + 16*((2*lg_t + (w>>1))&3)
        int srcA = lr + 16 * ((2 * lg) & 3);
        int srcB = lr + 16 * ((2 * lg + 1) & 3);
        bool hi = (lg >> 1) != 0;
        #pragma unroll
        for (int kk = 0; kk < 2; ++kk) {
          #pragma unroll
          for (int u = 0; u < 2; ++u) {
            unsigned a0 = (unsigned)__shfl((int)q32[2 * kk][u], srcA);
            unsigned a1 = (unsigned)__shfl((int)q32[2 * kk + 1][u], srcA);
            unsigned b0 = (unsigned)__shfl((int)q32[2 * kk][u], srcB);
            unsigned b1 = (unsigned)__shfl((int)q32[2 * kk + 1][u], srcB);
            pa[mi][kk].u[u] = hi ? a1 : a0;
            pa[mi][kk].u[2 + u] = hi ? b1 : b0;
          }
        }
      }
      // rescale O by corr broadcast to its row (row q = lg*4+j)
      #pragma unroll
      for (int mi = 0; mi < 2; ++mi)
        #pragma unroll
        for (int j = 0; j < 4; ++j) {
          float cj = __shfl(corr[mi], lg * 4 + j);
          #pragma unroll
          for (int c = 0; c < 4; ++c) o[mi][c][j] *= cj;
        }
      // ---- O += P·V (B-frag from V^T tile) ----
      #pragma unroll
      for (int c = 0; c < 4; ++c) {
        short8 vf0 = *(const short8*)&Vs[buf][(c * 16 + lr) * 64 + ((lg) ^ (lr & 7)) * 8];
        short8 vf1 = *(const short8*)&Vs[buf][(c * 16 + lr) * 64 + ((4 + lg) ^ (lr & 7)) * 8];
        #pragma unroll
        for (int mi = 0; mi < 2; ++mi) {
          o[mi][c] = __builtin_amdgcn_mfma_f32_16x16x32_bf16(pa[mi][0].s8, vf0, o[mi][c], 0, 0, 0);
          o[mi][c] = __builtin_amdgcn_mfma_f32_16x16x32_bf16(pa[mi][1].s8, vf1, o[mi][c], 0, 0, 0);
        }
      }
    }

    if (pre) {
      #pragma unroll
      for (int i = 0; i < 2; ++i) {
        int r = w * 16 + i * 8 + (l >> 3);
        int sl = (l & 7) ^ (r & 7);
        *(short8*)&Ks[buf ^ 1][r * 64 + sl * 8] = sk[i];
        *(short8*)&Vs[buf ^ 1][r * 64 + sl * 8] = sv[i];
      }
    }
    buf ^= 1;
  }

  // epilogue: normalize + write y [B, T, C]
  const int b = bh / H_, h = bh % H_;
  #pragma unroll
  for (int mi = 0; mi < 2; ++mi) {
    float linv[4];
    #pragma unroll
    for (int j = 0; j < 4; ++j) linv[j] = 1.0f / __shfl(ls[mi], lg * 4 + j);
    #pragma unroll
    for (int c = 0; c < 4; ++c)
      #pragma unroll
      for (int j = 0; j < 4; ++j) {
        int row = qbase + mi * 16 + lg * 4 + j;
        y[((size_t)b * T_ + row) * C_ + h * 64 + c * 16 + lr] = f2bf(o[mi][c][j] * linv[j]);
      }
  }
}

extern "C" void kernel_launch(void* const* d_in, const int* in_sizes, int n_in,
                              void* d_out, int out_size, void* d_ws, size_t ws_size,
                              hipStream_t stream) {
  const float* x  = (const float*)d_in[0];
  const float* Wq = (const float*)d_in[1];
  const float* bq = (const float*)d_in[2];
  const float* Wk = (const float*)d_in[3];
  const float* bk = (const float*)d_in[4];
  const float* Wv = (const float*)d_in[5];
  const float* bv = (const float*)d_in[6];
  const float* Wp = (const float*)d_in[7];
  const float* bp = (const float*)d_in[8];
  float* out = (float*)d_out;

  char* p = (char*)d_ws;
  auto alloc = [&](size_t bytes) { char* r = p; p += (bytes + 255) & ~255ULL; return r; };
  ushort* xb  = (ushort*)alloc((size_t)BT_ * C_ * 2);
  ushort* wqb = (ushort*)alloc((size_t)C_ * C_ * 2);
  ushort* wkb = (ushort*)alloc((size_t)C_ * C_ * 2);
  ushort* wvb = (ushort*)alloc((size_t)C_ * C_ * 2);
  ushort* wpb = (ushort*)alloc((size_t)C_ * C_ * 2);
  ushort* qb  = (ushort*)alloc((size_t)BT_ * C_ * 2);
  ushort* kb  = (ushort*)alloc((size_t)BT_ * C_ * 2);
  ushort* vtb = (ushort*)alloc((size_t)BT_ * C_ * 2);   // V^T [B,H,64,T]
  ushort* yb  = (ushort*)alloc((size_t)BT_ * C_ * 2);
  float* ctab = (float*)alloc((size_t)T_ * 32 * 4);
  float* stab = (float*)alloc((size_t)T_ * 32 * 4);

  k_f32_to_bf16<<<(BT_ * C_ / 4 + 255) / 256, 256, 0, stream>>>(x, xb, BT_ * C_ / 4);
  k_f32_to_bf16<<<(C_ * C_ / 4 + 255) / 256, 256, 0, stream>>>(Wq, wqb, C_ * C_ / 4);
  k_f32_to_bf16<<<(C_ * C_ / 4 + 255) / 256, 256, 0, stream>>>(Wk, wkb, C_ * C_ / 4);
  k_f32_to_bf16<<<(C_ * C_ / 4 + 255) / 256, 256, 0, stream>>>(Wv, wvb, C_ * C_ / 4);
  k_f32_to_bf16<<<(C_ * C_ / 4 + 255) / 256, 256, 0, stream>>>(Wp, wpb, C_ * C_ / 4);
  k_rope_tab<<<T_ * 32 / 256, 256, 0, stream>>>(ctab, stab);

  k_qkv_gemm<<<dim3(BT_ / 128, 2304 / 128), 256, 0, stream>>>(
      xb, wqb, wkb, wvb, bq, bk, bv, qb, kb, vtb);

  // q: fold 1/sqrt(D) * log2(e) so attn softmax runs in exp2 domain
  k_rope_apply<<<(B_ * H_ * T_ * 32) / 256, 256, 0, stream>>>(qb, ctab, stab, 0.125f * 1.4426950408889634f);
  k_rope_apply<<<(B_ * H_ * T_ * 32) / 256, 256, 0, stream>>>(kb, ctab, stab, 1.0f);

  k_attn<<<dim3(T_ / 128, B_ * H_), 256, 0, stream>>>(qb, kb, vtb, yb);

  k_proj_gemm<<<dim3(BT_ / 128, C_ / 128), 256, 0, stream>>>(yb, wpb, bp, out);
}

// Round 3
// 342.083 us; speedup vs baseline: 1.7491x; 1.2456x over previous
//
#include <hip/hip_runtime.h>
#include <hip/hip_bf16.h>

#define B_  2
#define T_  4096
#define C_  768
#define H_  12
#define D_  64
#define BT_ (B_*T_)   // 8192

typedef __attribute__((ext_vector_type(8))) short short8;
typedef __attribute__((ext_vector_type(4))) float f32x4;

union U32x4 { short8 s8; unsigned u[4]; };

__device__ __forceinline__ ushort f2bf(float f) {
  union { __hip_bfloat16 b; ushort u; } cv; cv.b = __float2bfloat16(f); return cv.u;
}
__device__ __forceinline__ float bf2f(ushort u) {
  unsigned x = ((unsigned)u) << 16; float f; __builtin_memcpy(&f, &x, 4); return f;
}
__device__ __forceinline__ unsigned pack2(float a, float b) {
  return (unsigned)f2bf(a) | ((unsigned)f2bf(b) << 16);
}

// ---------------- elementwise converts ----------------
__global__ void k_f32_to_bf16(const float* __restrict__ in, ushort* __restrict__ out, int n4) {
  int i = blockIdx.x * blockDim.x + threadIdx.x;
  if (i >= n4) return;
  const float4 v = ((const float4*)in)[i];
  ushort4 o;
  o.x = f2bf(v.x); o.y = f2bf(v.y); o.z = f2bf(v.z); o.w = f2bf(v.w);
  ((ushort4*)out)[i] = o;
}

__global__ void k_rope_tab(float* __restrict__ ctab, float* __restrict__ stab) {
  int i = blockIdx.x * blockDim.x + threadIdx.x;  // T_*32 threads
  int t = i >> 5, p = i & 31;
  float inv = 1.0f / powf(10000.0f, (2.0f * (float)p) / 64.0f);
  float a = (float)t * inv;
  ctab[i] = cosf(a); stab[i] = sinf(a);
}

// in-place RoPE on [B*H, T, 64] bf16; q gets 1/8*log2(e) folded (exp2-domain softmax)
__global__ void k_rope_apply(ushort* __restrict__ x, const float* __restrict__ ctab,
                             const float* __restrict__ stab, float scale) {
  int i = blockIdx.x * blockDim.x + threadIdx.x;  // B_*H_*T_*32 threads
  int p = i & 31, t = (i >> 5) & (T_ - 1);
  size_t base = ((size_t)(i >> 5)) * 64 + (size_t)p * 2;
  uint xv = *(const uint*)(x + base);
  float x1 = bf2f((ushort)(xv & 0xffffu)), x2 = bf2f((ushort)(xv >> 16));
  float c = ctab[t * 32 + p], s = stab[t * 32 + p];
  float o1 = (x1 * c - x2 * s) * scale, o2 = (x1 * s + x2 * c) * scale;
  *(uint*)(x + base) = (uint)f2bf(o1) | ((uint)f2bf(o2) << 16);
}

// ---------------- QKV projection GEMM ----------------
// q,k -> [B,H,T,64]; v -> TRANSPOSED [B,H,64,T] (attn consumes V^T fragments).
__global__ __launch_bounds__(256) void k_qkv_gemm(
    const ushort* __restrict__ xb, const ushort* __restrict__ wq,
    const ushort* __restrict__ wk, const ushort* __restrict__ wv,
    const float* __restrict__ bq, const float* __restrict__ bk, const float* __restrict__ bv,
    ushort* __restrict__ qo, ushort* __restrict__ ko, ushort* __restrict__ vo) {
  __shared__ __align__(16) ushort As[128 * 72];
  __shared__ __align__(16) ushort Bs[128 * 72];
  const int tid = threadIdx.x, l = tid & 63, w = tid >> 6;
  const int lr = l & 15, lg = l >> 4;
  const int m0 = blockIdx.x * 128;
  const int n0g = blockIdx.y * 128;
  const int proj = n0g / 768;
  const int n0 = n0g % 768;
  const ushort* wsrc = proj == 0 ? wq : (proj == 1 ? wk : wv);
  const int wr = (w >> 1) * 64, wc = (w & 1) * 64;

  f32x4 acc[4][4];
  #pragma unroll
  for (int a = 0; a < 4; ++a)
    #pragma unroll
    for (int b = 0; b < 4; ++b) acc[a][b] = (f32x4){0.f, 0.f, 0.f, 0.f};

  for (int k0 = 0; k0 < 768; k0 += 64) {
    #pragma unroll
    for (int i = 0; i < 4; ++i) {
      int seg = tid + i * 256;
      int row = seg >> 3, c8 = (seg & 7) << 3;
      *(short8*)&As[row * 72 + c8] = *(const short8*)(xb + (size_t)(m0 + row) * 768 + k0 + c8);
      *(short8*)&Bs[row * 72 + c8] = *(const short8*)(wsrc + (size_t)(n0 + row) * 768 + k0 + c8);
    }
    __syncthreads();
    #pragma unroll
    for (int kk = 0; kk < 2; ++kk) {
      short8 af[4], bf[4];
      #pragma unroll
      for (int mi = 0; mi < 4; ++mi)
        af[mi] = *(const short8*)&As[(wr + mi * 16 + lr) * 72 + kk * 32 + lg * 8];
      #pragma unroll
      for (int ni = 0; ni < 4; ++ni)
        bf[ni] = *(const short8*)&Bs[(wc + ni * 16 + lr) * 72 + kk * 32 + lg * 8];
      #pragma unroll
      for (int mi = 0; mi < 4; ++mi)
        #pragma unroll
        for (int ni = 0; ni < 4; ++ni)
          acc[mi][ni] = __builtin_amdgcn_mfma_f32_16x16x32_bf16(af[mi], bf[ni], acc[mi][ni], 0, 0, 0);
    }
    __syncthreads();
  }

  const float* bias = proj == 0 ? bq : (proj == 1 ? bk : bv);
  if (proj == 2) {
    // V^T epilogue: vo[((b*H+h)*64 + d)*T + t], 4 consecutive t per lane (j-quad)
    #pragma unroll
    for (int mi = 0; mi < 4; ++mi) {
      #pragma unroll
      for (int ni = 0; ni < 4; ++ni) {
        int colc = n0 + wc + ni * 16 + lr;
        float bb = bias[colc];
        int h = colc >> 6, d = colc & 63;
        int row0 = m0 + wr + mi * 16 + lg * 4;
        int b = row0 >> 12, t0 = row0 & (T_ - 1);
        ushort4 pk;
        pk.x = f2bf(acc[mi][ni][0] + bb);
        pk.y = f2bf(acc[mi][ni][1] + bb);
        pk.z = f2bf(acc[mi][ni][2] + bb);
        pk.w = f2bf(acc[mi][ni][3] + bb);
        *(ushort4*)(vo + (((size_t)b * H_ + h) * 64 + d) * T_ + t0) = pk;
      }
    }
  } else {
    ushort* dst = proj == 0 ? qo : ko;
    #pragma unroll
    for (int mi = 0; mi < 4; ++mi) {
      #pragma unroll
      for (int ni = 0; ni < 4; ++ni) {
        int colc = n0 + wc + ni * 16 + lr;
        float bb = bias[colc];
        int h = colc >> 6, d = colc & 63;
        #pragma unroll
        for (int j = 0; j < 4; ++j) {
          int row = m0 + wr + mi * 16 + lg * 4 + j;
          int b = row >> 12, t = row & (T_ - 1);
          dst[((((size_t)b * H_ + h) << 12) + t) * 64 + d] = f2bf(acc[mi][ni][j] + bb);
        }
      }
    }
  }
}

// ---------------- output projection GEMM (f32 out) ----------------
__global__ __launch_bounds__(256) void k_proj_gemm(
    const ushort* __restrict__ yb, const ushort* __restrict__ wp,
    const float* __restrict__ bp, float* __restrict__ out) {
  __shared__ __align__(16) ushort As[128 * 72];
  __shared__ __align__(16) ushort Bs[128 * 72];
  const int tid = threadIdx.x, l = tid & 63, w = tid >> 6;
  const int lr = l & 15, lg = l >> 4;
  const int m0 = blockIdx.x * 128;
  const int n0 = blockIdx.y * 128;
  const int wr = (w >> 1) * 64, wc = (w & 1) * 64;

  f32x4 acc[4][4];
  #pragma unroll
  for (int a = 0; a < 4; ++a)
    #pragma unroll
    for (int b = 0; b < 4; ++b) acc[a][b] = (f32x4){0.f, 0.f, 0.f, 0.f};

  for (int k0 = 0; k0 < 768; k0 += 64) {
    #pragma unroll
    for (int i = 0; i < 4; ++i) {
      int seg = tid + i * 256;
      int row = seg >> 3, c8 = (seg & 7) << 3;
      *(short8*)&As[row * 72 + c8] = *(const short8*)(yb + (size_t)(m0 + row) * 768 + k0 + c8);
      *(short8*)&Bs[row * 72 + c8] = *(const short8*)(wp + (size_t)(n0 + row) * 768 + k0 + c8);
    }
    __syncthreads();
    #pragma unroll
    for (int kk = 0; kk < 2; ++kk) {
      short8 af[4], bf[4];
      #pragma unroll
      for (int mi = 0; mi < 4; ++mi)
        af[mi] = *(const short8*)&As[(wr + mi * 16 + lr) * 72 + kk * 32 + lg * 8];
      #pragma unroll
      for (int ni = 0; ni < 4; ++ni)
        bf[ni] = *(const short8*)&Bs[(wc + ni * 16 + lr) * 72 + kk * 32 + lg * 8];
      #pragma unroll
      for (int mi = 0; mi < 4; ++mi)
        #pragma unroll
        for (int ni = 0; ni < 4; ++ni)
          acc[mi][ni] = __builtin_amdgcn_mfma_f32_16x16x32_bf16(af[mi], bf[ni], acc[mi][ni], 0, 0, 0);
    }
    __syncthreads();
  }

  #pragma unroll
  for (int mi = 0; mi < 4; ++mi)
    #pragma unroll
    for (int ni = 0; ni < 4; ++ni) {
      int col = n0 + wc + ni * 16 + lr;
      float bb = bp[col];
      #pragma unroll
      for (int j = 0; j < 4; ++j) {
        int row = m0 + wr + mi * 16 + lg * 4 + j;
        out[(size_t)row * 768 + col] = acc[mi][ni][j] + bb;
      }
    }
}

// ---------------- causal flash attention ----------------
// Balanced pairing: grid (32, B*H); block p owns q-tiles lo=p, hi=63-p (64 rows
// each, wave w takes rows +16w of both). Every block = exactly 65 wave-tile
// computes -> no tail imbalance. O^T = V^T P^T formulation: softmax state is
// lane-local (q = lane&15). KBLK=64 double-buffered swizzled LDS; exp2 domain.
#define SOFTMAX_HALF(MI, DIAG) do { \
    if (kt == (DIAG)) { \
      const int qg = qrow[MI]; \
      _Pragma("unroll") for (int c = 0; c < 4; ++c) { \
        _Pragma("unroll") for (int j = 0; j < 4; ++j) \
          if (kt * 64 + c * 16 + lg * 4 + j > qg) sT[MI][c][j] = -1e30f; } \
    } \
    float vmax = sT[MI][0][0]; \
    _Pragma("unroll") for (int c = 0; c < 4; ++c) { \
      _Pragma("unroll") for (int j = 0; j < 4; ++j) vmax = fmaxf(vmax, sT[MI][c][j]); } \
    vmax = fmaxf(vmax, __shfl_xor(vmax, 16)); \
    vmax = fmaxf(vmax, __shfl_xor(vmax, 32)); \
    const float mn = fmaxf(mx[MI], vmax); \
    corr[MI] = exp2f(mx[MI] - mn); \
    mx[MI] = mn; \
    float rs = 0.f; unsigned q32[4][2]; \
    _Pragma("unroll") for (int c = 0; c < 4; ++c) { \
      float p0 = exp2f(sT[MI][c][0] - mn); \
      float p1 = exp2f(sT[MI][c][1] - mn); \
      float p2 = exp2f(sT[MI][c][2] - mn); \
      float p3 = exp2f(sT[MI][c][3] - mn); \
      rs += (p0 + p1) + (p2 + p3); \
      q32[c][0] = pack2(p0, p1); q32[c][1] = pack2(p2, p3); \
    } \
    rs += __shfl_xor(rs, 16); \
    rs += __shfl_xor(rs, 32); \
    ls[MI] = ls[MI] * corr[MI] + rs; \
    { const int srcA = lr + ((2 * (lg & 1)) << 4); \
      const int srcB = srcA + 16; \
      const bool hic = (lg & 2) != 0; \
      _Pragma("unroll") for (int kk = 0; kk < 2; ++kk) { \
        unsigned aA0 = (unsigned)__shfl((int)q32[2 * kk][0], srcA); \
        unsigned aA1 = (unsigned)__shfl((int)q32[2 * kk + 1][0], srcA); \
        unsigned bA0 = (unsigned)__shfl((int)q32[2 * kk][1], srcA); \
        unsigned bA1 = (unsigned)__shfl((int)q32[2 * kk + 1][1], srcA); \
        unsigned aB0 = (unsigned)__shfl((int)q32[2 * kk][0], srcB); \
        unsigned aB1 = (unsigned)__shfl((int)q32[2 * kk + 1][0], srcB); \
        unsigned bB0 = (unsigned)__shfl((int)q32[2 * kk][1], srcB); \
        unsigned bB1 = (unsigned)__shfl((int)q32[2 * kk + 1][1], srcB); \
        pa[MI][kk].u[0] = hic ? aA1 : aA0; \
        pa[MI][kk].u[1] = hic ? bA1 : bA0; \
        pa[MI][kk].u[2] = hic ? aB1 : aB0; \
        pa[MI][kk].u[3] = hic ? bB1 : bB0; \
      } } \
  } while (0)

__global__ __launch_bounds__(256) void k_attn(
    const ushort* __restrict__ q, const ushort* __restrict__ k,
    const ushort* __restrict__ vt, ushort* __restrict__ y) {
  __shared__ __align__(16) ushort Ks[2][64 * 64];
  __shared__ __align__(16) ushort Vs[2][64 * 64];
  const int tid = threadIdx.x, l = tid & 63, w = tid >> 6;
  const int lr = l & 15, lg = l >> 4;
  const int p = blockIdx.x;            // pair id 0..31
  const int bh = blockIdx.y;
  const size_t kpl = (size_t)bh * T_ * 64;
  const size_t vpl = (size_t)bh * 64 * T_;
  const int tlo = p, thi = 63 - p;
  const int qrow[2] = { tlo * 64 + w * 16 + lr, thi * 64 + w * 16 + lr };
  const int nt = thi + 1;

  // Q fragments (B operand of S^T = K·Q: col=q=lane&15, k-rows = d)
  short8 qf[2][2];
  #pragma unroll
  for (int mi = 0; mi < 2; ++mi)
    #pragma unroll
    for (int kk = 0; kk < 2; ++kk)
      qf[mi][kk] = *(const short8*)(q + kpl + (size_t)qrow[mi] * 64 + kk * 32 + lg * 8);

  f32x4 o[2][4];
  float mx[2], ls[2];
  #pragma unroll
  for (int mi = 0; mi < 2; ++mi) {
    mx[mi] = -1e30f; ls[mi] = 0.f;
    #pragma unroll
    for (int c = 0; c < 4; ++c) o[mi][c] = (f32x4){0.f, 0.f, 0.f, 0.f};
  }

  // prologue: stage tile 0 into buf 0 (XOR-swizzled 16B slots)
  {
    #pragma unroll
    for (int i = 0; i < 2; ++i) {
      const int r = w * 16 + i * 8 + (l >> 3);
      const int sl = (l & 7) ^ (r & 7);
      short8 s0 = *(const short8*)(k + kpl + (size_t)r * 64 + (l & 7) * 8);
      short8 v0 = *(const short8*)(vt + vpl + (size_t)r * T_ + (l & 7) * 8);
      *(short8*)&Ks[0][r * 64 + sl * 8] = s0;
      *(short8*)&Vs[0][r * 64 + sl * 8] = v0;
    }
  }

  int buf = 0;
  for (int kt = 0; kt < nt; ++kt) {
    __syncthreads();
    // async-split staging: issue next tile's global loads before compute
    short8 sk[2], sv[2];
    const bool pre = (kt + 1 < nt);
    if (pre) {
      #pragma unroll
      for (int i = 0; i < 2; ++i) {
        const int r = w * 16 + i * 8 + (l >> 3);
        sk[i] = *(const short8*)(k + kpl + (size_t)((kt + 1) * 64 + r) * 64 + (l & 7) * 8);
        sv[i] = *(const short8*)(vt + vpl + (size_t)r * T_ + (kt + 1) * 64 + (l & 7) * 8);
      }
    }
    const bool lo_act = (kt <= tlo);   // hi half always active (kt < nt = thi+1)

    // ---- S^T = K·Q ----
    f32x4 sT[2][4];
    #pragma unroll
    for (int c = 0; c < 4; ++c) {
      short8 kf0 = *(const short8*)&Ks[buf][(c * 16 + lr) * 64 + ((lg) ^ (lr & 7)) * 8];
      short8 kf1 = *(const short8*)&Ks[buf][(c * 16 + lr) * 64 + ((4 + lg) ^ (lr & 7)) * 8];
      f32x4 z1 = (f32x4){0.f, 0.f, 0.f, 0.f};
      z1 = __builtin_amdgcn_mfma_f32_16x16x32_bf16(kf0, qf[1][0], z1, 0, 0, 0);
      z1 = __builtin_amdgcn_mfma_f32_16x16x32_bf16(kf1, qf[1][1], z1, 0, 0, 0);
      sT[1][c] = z1;
      if (lo_act) {
        f32x4 z0 = (f32x4){0.f, 0.f, 0.f, 0.f};
        z0 = __builtin_amdgcn_mfma_f32_16x16x32_bf16(kf0, qf[0][0], z0, 0, 0, 0);
        z0 = __builtin_amdgcn_mfma_f32_16x16x32_bf16(kf1, qf[0][1], z0, 0, 0, 0);
        sT[0][c] = z0;
      }
    }

    // ---- softmax + P^T B-frag exchange (lane-local state, q = lr) ----
    U32x4 pa[2][2];
    float corr[2];
    SOFTMAX_HALF(1, thi);
    if (lo_act) SOFTMAX_HALF(0, tlo);

    // ---- O^T += V^T·P^T ----
    #pragma unroll
    for (int c = 0; c < 4; ++c) {
      short8 vf0 = *(const short8*)&Vs[buf][(c * 16 + lr) * 64 + ((lg) ^ (lr & 7)) * 8];
      short8 vf1 = *(const short8*)&Vs[buf][(c * 16 + lr) * 64 + ((4 + lg) ^ (lr & 7)) * 8];
      o[1][c] *= corr[1];
      o[1][c] = __builtin_amdgcn_mfma_f32_16x16x32_bf16(vf0, pa[1][0].s8, o[1][c], 0, 0, 0);
      o[1][c] = __builtin_amdgcn_mfma_f32_16x16x32_bf16(vf1, pa[1][1].s8, o[1][c], 0, 0, 0);
      if (lo_act) {
        o[0][c] *= corr[0];
        o[0][c] = __builtin_amdgcn_mfma_f32_16x16x32_bf16(vf0, pa[0][0].s8, o[0][c], 0, 0, 0);
        o[0][c] = __builtin_amdgcn_mfma_f32_16x16x32_bf16(vf1, pa[0][1].s8, o[0][c], 0, 0, 0);
      }
    }

    if (pre) {
      #pragma unroll
      for (int i = 0; i < 2; ++i) {
        const int r = w * 16 + i * 8 + (l >> 3);
        const int sl = (l & 7) ^ (r & 7);
        *(short8*)&Ks[buf ^ 1][r * 64 + sl * 8] = sk[i];
        *(short8*)&Vs[buf ^ 1][r * 64 + sl * 8] = sv[i];
      }
    }
    buf ^= 1;
  }

  // epilogue: normalize (lane-local) + write y [B, T, C]; O^T frag: col q = lr,
  // row d = c*16 + lg*4 + j -> ushort4 per (mi,c)
  const int b = bh / H_, h = bh % H_;
  #pragma unroll
  for (int mi = 0; mi < 2; ++mi) {
    const float linv = 1.0f / ls[mi];
    const size_t base = ((size_t)b * T_ + qrow[mi]) * C_ + h * 64;
    #pragma unroll
    for (int c = 0; c < 4; ++c) {
      ushort4 pk;
      pk.x = f2bf(o[mi][c][0] * linv);
      pk.y = f2bf(o[mi][c][1] * linv);
      pk.z = f2bf(o[mi][c][2] * linv);
      pk.w = f2bf(o[mi][c][3] * linv);
      *(ushort4*)(y + base + c * 16 + lg * 4) = pk;
    }
  }
}

extern "C" void kernel_launch(void* const* d_in, const int* in_sizes, int n_in,
                              void* d_out, int out_size, void* d_ws, size_t ws_size,
                              hipStream_t stream) {
  const float* x  = (const float*)d_in[0];
  const float* Wq = (const float*)d_in[1];
  const float* bq = (const float*)d_in[2];
  const float* Wk = (const float*)d_in[3];
  const float* bk = (const float*)d_in[4];
  const float* Wv = (const float*)d_in[5];
  const float* bv = (const float*)d_in[6];
  const float* Wp = (const float*)d_in[7];
  const float* bp = (const float*)d_in[8];
  float* out = (float*)d_out;

  char* p = (char*)d_ws;
  auto alloc = [&](size_t bytes) { char* r = p; p += (bytes + 255) & ~255ULL; return r; };
  ushort* xb  = (ushort*)alloc((size_t)BT_ * C_ * 2);
  ushort* wqb = (ushort*)alloc((size_t)C_ * C_ * 2);
  ushort* wkb = (ushort*)alloc((size_t)C_ * C_ * 2);
  ushort* wvb = (ushort*)alloc((size_t)C_ * C_ * 2);
  ushort* wpb = (ushort*)alloc((size_t)C_ * C_ * 2);
  ushort* qb  = (ushort*)alloc((size_t)BT_ * C_ * 2);
  ushort* kb  = (ushort*)alloc((size_t)BT_ * C_ * 2);
  ushort* vtb = (ushort*)alloc((size_t)BT_ * C_ * 2);   // V^T [B,H,64,T]
  ushort* yb  = (ushort*)alloc((size_t)BT_ * C_ * 2);
  float* ctab = (float*)alloc((size_t)T_ * 32 * 4);
  float* stab = (float*)alloc((size_t)T_ * 32 * 4);

  k_f32_to_bf16<<<(BT_ * C_ / 4 + 255) / 256, 256, 0, stream>>>(x, xb, BT_ * C_ / 4);
  k_f32_to_bf16<<<(C_ * C_ / 4 + 255) / 256, 256, 0, stream>>>(Wq, wqb, C_ * C_ / 4);
  k_f32_to_bf16<<<(C_ * C_ / 4 + 255) / 256, 256, 0, stream>>>(Wk, wkb, C_ * C_ / 4);
  k_f32_to_bf16<<<(C_ * C_ / 4 + 255) / 256, 256, 0, stream>>>(Wv, wvb, C_ * C_ / 4);
  k_f32_to_bf16<<<(C_ * C_ / 4 + 255) / 256, 256, 0, stream>>>(Wp, wpb, C_ * C_ / 4);
  k_rope_tab<<<T_ * 32 / 256, 256, 0, stream>>>(ctab, stab);

  k_qkv_gemm<<<dim3(BT_ / 128, 2304 / 128), 256, 0, stream>>>(
      xb, wqb, wkb, wvb, bq, bk, bv, qb, kb, vtb);

  // q: fold 1/sqrt(D) * log2(e) so attn softmax runs in exp2 domain
  k_rope_apply<<<(B_ * H_ * T_ * 32) / 256, 256, 0, stream>>>(qb, ctab, stab, 0.125f * 1.4426950408889634f);
  k_rope_apply<<<(B_ * H_ * T_ * 32) / 256, 256, 0, stream>>>(kb, ctab, stab, 1.0f);

  k_attn<<<dim3(32, B_ * H_), 256, 0, stream>>>(qb, kb, vtb, yb);

  k_proj_gemm<<<dim3(BT_ / 128, C_ / 128), 256, 0, stream>>>(yb, wpb, bp, out);
}

// Round 6
// 257.581 us; speedup vs baseline: 2.3229x; 1.3281x over previous
//
#include <hip/hip_runtime.h>
#include <hip/hip_bf16.h>

#define B_  2
#define T_  4096
#define C_  768
#define H_  12
#define D_  64
#define BT_ (B_*T_)   // 8192

typedef __attribute__((ext_vector_type(8))) short short8;
typedef __attribute__((ext_vector_type(4))) float f32x4;

union U32x4 { short8 s8; unsigned u[4]; };

__device__ __forceinline__ ushort f2bf(float f) {
  union { __hip_bfloat16 b; ushort u; } cv; cv.b = __float2bfloat16(f); return cv.u;
}
__device__ __forceinline__ float bf2f(ushort u) {
  unsigned x = ((unsigned)u) << 16; float f; __builtin_memcpy(&f, &x, 4); return f;
}
__device__ __forceinline__ unsigned pack2(float a, float b) {
  return (unsigned)f2bf(a) | ((unsigned)f2bf(b) << 16);
}

// ---------------- elementwise converts ----------------
__global__ void k_f32_to_bf16(const float* __restrict__ in, ushort* __restrict__ out, int n4) {
  int i = blockIdx.x * blockDim.x + threadIdx.x;
  if (i >= n4) return;
  const float4 v = ((const float4*)in)[i];
  ushort4 o;
  o.x = f2bf(v.x); o.y = f2bf(v.y); o.z = f2bf(v.z); o.w = f2bf(v.w);
  ((ushort4*)out)[i] = o;
}

__global__ void k_rope_tab(float* __restrict__ ctab, float* __restrict__ stab) {
  int i = blockIdx.x * blockDim.x + threadIdx.x;  // T_*32 threads
  int t = i >> 5, p = i & 31;
  float inv = 1.0f / powf(10000.0f, (2.0f * (float)p) / 64.0f);
  float a = (float)t * inv;
  ctab[i] = cosf(a); stab[i] = sinf(a);
}

// in-place RoPE on [B*H, T, 64] bf16; q gets 1/8*log2(e) folded (exp2-domain softmax)
__global__ void k_rope_apply(ushort* __restrict__ x, const float* __restrict__ ctab,
                             const float* __restrict__ stab, float scale) {
  int i = blockIdx.x * blockDim.x + threadIdx.x;  // B_*H_*T_*32 threads
  int p = i & 31, t = (i >> 5) & (T_ - 1);
  size_t base = ((size_t)(i >> 5)) * 64 + (size_t)p * 2;
  uint xv = *(const uint*)(x + base);
  float x1 = bf2f((ushort)(xv & 0xffffu)), x2 = bf2f((ushort)(xv >> 16));
  float c = ctab[t * 32 + p], s = stab[t * 32 + p];
  float o1 = (x1 * c - x2 * s) * scale, o2 = (x1 * s + x2 * c) * scale;
  *(uint*)(x + base) = (uint)f2bf(o1) | ((uint)f2bf(o2) << 16);
}

// ---------------- QKV projection GEMM ----------------
// q,k -> [B,H,T,64]; v -> TRANSPOSED [B,H,64,T] (attn consumes V^T fragments).
__global__ __launch_bounds__(256) void k_qkv_gemm(
    const ushort* __restrict__ xb, const ushort* __restrict__ wq,
    const ushort* __restrict__ wk, const ushort* __restrict__ wv,
    const float* __restrict__ bq, const float* __restrict__ bk, const float* __restrict__ bv,
    ushort* __restrict__ qo, ushort* __restrict__ ko, ushort* __restrict__ vo) {
  __shared__ __align__(16) ushort As[128 * 72];
  __shared__ __align__(16) ushort Bs[128 * 72];
  const int tid = threadIdx.x, l = tid & 63, w = tid >> 6;
  const int lr = l & 15, lg = l >> 4;
  const int m0 = blockIdx.x * 128;
  const int n0g = blockIdx.y * 128;
  const int proj = n0g / 768;
  const int n0 = n0g % 768;
  const ushort* wsrc = proj == 0 ? wq : (proj == 1 ? wk : wv);
  const int wr = (w >> 1) * 64, wc = (w & 1) * 64;

  f32x4 acc[4][4];
  #pragma unroll
  for (int a = 0; a < 4; ++a)
    #pragma unroll
    for (int b = 0; b < 4; ++b) acc[a][b] = (f32x4){0.f, 0.f, 0.f, 0.f};

  for (int k0 = 0; k0 < 768; k0 += 64) {
    #pragma unroll
    for (int i = 0; i < 4; ++i) {
      int seg = tid + i * 256;
      int row = seg >> 3, c8 = (seg & 7) << 3;
      *(short8*)&As[row * 72 + c8] = *(const short8*)(xb + (size_t)(m0 + row) * 768 + k0 + c8);
      *(short8*)&Bs[row * 72 + c8] = *(const short8*)(wsrc + (size_t)(n0 + row) * 768 + k0 + c8);
    }
    __syncthreads();
    #pragma unroll
    for (int kk = 0; kk < 2; ++kk) {
      short8 af[4], bf[4];
      #pragma unroll
      for (int mi = 0; mi < 4; ++mi)
        af[mi] = *(const short8*)&As[(wr + mi * 16 + lr) * 72 + kk * 32 + lg * 8];
      #pragma unroll
      for (int ni = 0; ni < 4; ++ni)
        bf[ni] = *(const short8*)&Bs[(wc + ni * 16 + lr) * 72 + kk * 32 + lg * 8];
      #pragma unroll
      for (int mi = 0; mi < 4; ++mi)
        #pragma unroll
        for (int ni = 0; ni < 4; ++ni)
          acc[mi][ni] = __builtin_amdgcn_mfma_f32_16x16x32_bf16(af[mi], bf[ni], acc[mi][ni], 0, 0, 0);
    }
    __syncthreads();
  }

  const float* bias = proj == 0 ? bq : (proj == 1 ? bk : bv);
  if (proj == 2) {
    #pragma unroll
    for (int mi = 0; mi < 4; ++mi) {
      #pragma unroll
      for (int ni = 0; ni < 4; ++ni) {
        int colc = n0 + wc + ni * 16 + lr;
        float bb = bias[colc];
        int h = colc >> 6, d = colc & 63;
        int row0 = m0 + wr + mi * 16 + lg * 4;
        int b = row0 >> 12, t0 = row0 & (T_ - 1);
        ushort4 pk;
        pk.x = f2bf(acc[mi][ni][0] + bb);
        pk.y = f2bf(acc[mi][ni][1] + bb);
        pk.z = f2bf(acc[mi][ni][2] + bb);
        pk.w = f2bf(acc[mi][ni][3] + bb);
        *(ushort4*)(vo + (((size_t)b * H_ + h) * 64 + d) * T_ + t0) = pk;
      }
    }
  } else {
    ushort* dst = proj == 0 ? qo : ko;
    #pragma unroll
    for (int mi = 0; mi < 4; ++mi) {
      #pragma unroll
      for (int ni = 0; ni < 4; ++ni) {
        int colc = n0 + wc + ni * 16 + lr;
        float bb = bias[colc];
        int h = colc >> 6, d = colc & 63;
        #pragma unroll
        for (int j = 0; j < 4; ++j) {
          int row = m0 + wr + mi * 16 + lg * 4 + j;
          int b = row >> 12, t = row & (T_ - 1);
          dst[((((size_t)b * H_ + h) << 12) + t) * 64 + d] = f2bf(acc[mi][ni][j] + bb);
        }
      }
    }
  }
}

// ---------------- output projection GEMM (f32 out) ----------------
__global__ __launch_bounds__(256) void k_proj_gemm(
    const ushort* __restrict__ yb, const ushort* __restrict__ wp,
    const float* __restrict__ bp, float* __restrict__ out) {
  __shared__ __align__(16) ushort As[128 * 72];
  __shared__ __align__(16) ushort Bs[128 * 72];
  const int tid = threadIdx.x, l = tid & 63, w = tid >> 6;
  const int lr = l & 15, lg = l >> 4;
  const int m0 = blockIdx.x * 128;
  const int n0 = blockIdx.y * 128;
  const int wr = (w >> 1) * 64, wc = (w & 1) * 64;

  f32x4 acc[4][4];
  #pragma unroll
  for (int a = 0; a < 4; ++a)
    #pragma unroll
    for (int b = 0; b < 4; ++b) acc[a][b] = (f32x4){0.f, 0.f, 0.f, 0.f};

  for (int k0 = 0; k0 < 768; k0 += 64) {
    #pragma unroll
    for (int i = 0; i < 4; ++i) {
      int seg = tid + i * 256;
      int row = seg >> 3, c8 = (seg & 7) << 3;
      *(short8*)&As[row * 72 + c8] = *(const short8*)(yb + (size_t)(m0 + row) * 768 + k0 + c8);
      *(short8*)&Bs[row * 72 + c8] = *(const short8*)(wp + (size_t)(n0 + row) * 768 + k0 + c8);
    }
    __syncthreads();
    #pragma unroll
    for (int kk = 0; kk < 2; ++kk) {
      short8 af[4], bf[4];
      #pragma unroll
      for (int mi = 0; mi < 4; ++mi)
        af[mi] = *(const short8*)&As[(wr + mi * 16 + lr) * 72 + kk * 32 + lg * 8];
      #pragma unroll
      for (int ni = 0; ni < 4; ++ni)
        bf[ni] = *(const short8*)&Bs[(wc + ni * 16 + lr) * 72 + kk * 32 + lg * 8];
      #pragma unroll
      for (int mi = 0; mi < 4; ++mi)
        #pragma unroll
        for (int ni = 0; ni < 4; ++ni)
          acc[mi][ni] = __builtin_amdgcn_mfma_f32_16x16x32_bf16(af[mi], bf[ni], acc[mi][ni], 0, 0, 0);
    }
    __syncthreads();
  }

  #pragma unroll
  for (int mi = 0; mi < 4; ++mi)
    #pragma unroll
    for (int ni = 0; ni < 4; ++ni) {
      int col = n0 + wc + ni * 16 + lr;
      float bb = bp[col];
      #pragma unroll
      for (int j = 0; j < 4; ++j) {
        int row = m0 + wr + mi * 16 + lg * 4 + j;
        out[(size_t)row * 768 + col] = acc[mi][ni][j] + bb;
      }
    }
}

// ---------------- causal flash attention: one 64-row q-tile per block ----------
// grid 1536 1-D. Balanced mapping: v=(bid&255)*6+(bid>>8); u=v&63;
// t = (u&1) ? 63-(u>>1) : (u>>1); bh = v>>6.  Consecutive v pair (t, 63-t) =
// 65 units; each CU's 6 static bids = 3 complementary pairs = exactly 195
// units; non-resident tail dispatched dynamically in balanced pairs.
// O^T = V^T P^T (lane-local softmax state, q = lane&15), exp2 domain,
// double-buffered XOR-swizzled LDS, R3-proven shfl P-exchange.
__global__ __launch_bounds__(256) void k_attn(
    const ushort* __restrict__ q, const ushort* __restrict__ k,
    const ushort* __restrict__ vt, ushort* __restrict__ y) {
  __shared__ __align__(16) ushort Ks[2][64 * 64];
  __shared__ __align__(16) ushort Vs[2][64 * 64];
  const int tid = threadIdx.x, l = tid & 63, w = tid >> 6;
  const int lr = l & 15, lg = l >> 4;
  const int bid = blockIdx.x;
  const int v = (bid & 255) * 6 + (bid >> 8);
  const int u = v & 63;
  const int t = (u & 1) ? 63 - (u >> 1) : (u >> 1);
  const int bh = v >> 6;
  const size_t kpl = (size_t)bh * T_ * 64;
  const size_t vpl = (size_t)bh * 64 * T_;
  const int qrow = t * 64 + w * 16 + lr;
  const int nt = t + 1;

  // Q fragments (B operand of S^T = K·Q: col=q=lane&15, k-rows = d)
  short8 qf[2];
  #pragma unroll
  for (int kk = 0; kk < 2; ++kk)
    qf[kk] = *(const short8*)(q + kpl + (size_t)qrow * 64 + kk * 32 + lg * 8);

  f32x4 o[4];
  float mx = -1e30f, ls = 0.f;
  #pragma unroll
  for (int c = 0; c < 4; ++c) o[c] = (f32x4){0.f, 0.f, 0.f, 0.f};

  // prologue: stage tile 0 into buf 0 (XOR-swizzled 16B slots)
  {
    #pragma unroll
    for (int i = 0; i < 2; ++i) {
      const int r = w * 16 + i * 8 + (l >> 3);
      const int sl = (l & 7) ^ (r & 7);
      short8 s0 = *(const short8*)(k + kpl + (size_t)r * 64 + (l & 7) * 8);
      short8 v0 = *(const short8*)(vt + vpl + (size_t)r * T_ + (l & 7) * 8);
      *(short8*)&Ks[0][r * 64 + sl * 8] = s0;
      *(short8*)&Vs[0][r * 64 + sl * 8] = v0;
    }
  }

  int buf = 0;
  for (int kt = 0; kt < nt; ++kt) {
    __syncthreads();
    // async-split staging: issue next tile's global loads before compute
    short8 sk[2], sv[2];
    const bool pre = (kt + 1 < nt);
    if (pre) {
      #pragma unroll
      for (int i = 0; i < 2; ++i) {
        const int r = w * 16 + i * 8 + (l >> 3);
        sk[i] = *(const short8*)(k + kpl + (size_t)((kt + 1) * 64 + r) * 64 + (l & 7) * 8);
        sv[i] = *(const short8*)(vt + vpl + (size_t)r * T_ + (kt + 1) * 64 + (l & 7) * 8);
      }
    }

    // ---- S^T = K·Q ----
    f32x4 sT[4];
    #pragma unroll
    for (int c = 0; c < 4; ++c) {
      short8 kf0 = *(const short8*)&Ks[buf][(c * 16 + lr) * 64 + ((lg) ^ (lr & 7)) * 8];
      short8 kf1 = *(const short8*)&Ks[buf][(c * 16 + lr) * 64 + ((4 + lg) ^ (lr & 7)) * 8];
      f32x4 z = (f32x4){0.f, 0.f, 0.f, 0.f};
      z = __builtin_amdgcn_mfma_f32_16x16x32_bf16(kf0, qf[0], z, 0, 0, 0);
      z = __builtin_amdgcn_mfma_f32_16x16x32_bf16(kf1, qf[1], z, 0, 0, 0);
      sT[c] = z;
    }

    // ---- softmax (lane-local state, q = lr) ----
    if (kt == t) {   // diagonal tile: causal mask (S^T row=key, col=q)
      #pragma unroll
      for (int c = 0; c < 4; ++c)
        #pragma unroll
        for (int j = 0; j < 4; ++j)
          if (kt * 64 + c * 16 + lg * 4 + j > qrow) sT[c][j] = -1e30f;
    }
    float vmax = sT[0][0];
    #pragma unroll
    for (int c = 0; c < 4; ++c)
      #pragma unroll
      for (int j = 0; j < 4; ++j) vmax = fmaxf(vmax, sT[c][j]);
    vmax = fmaxf(vmax, __shfl_xor(vmax, 16));
    vmax = fmaxf(vmax, __shfl_xor(vmax, 32));
    const float mn = fmaxf(mx, vmax);
    const float corr = exp2f(mx - mn);
    mx = mn;
    float rs = 0.f;
    unsigned q32[4][2];
    #pragma unroll
    for (int c = 0; c < 4; ++c) {
      float p0 = exp2f(sT[c][0] - mn);
      float p1 = exp2f(sT[c][1] - mn);
      float p2 = exp2f(sT[c][2] - mn);
      float p3 = exp2f(sT[c][3] - mn);
      rs += (p0 + p1) + (p2 + p3);
      q32[c][0] = pack2(p0, p1); q32[c][1] = pack2(p2, p3);
    }
    rs += __shfl_xor(rs, 16);
    rs += __shfl_xor(rs, 32);
    ls = ls * corr + rs;

    // ---- P^T B-frag exchange (R3-proven shfl network) ----
    U32x4 pa[2];
    {
      const int srcA = lr + ((2 * (lg & 1)) << 4);
      const int srcB = srcA + 16;
      const bool hic = (lg & 2) != 0;
      #pragma unroll
      for (int kk = 0; kk < 2; ++kk) {
        unsigned aA0 = (unsigned)__shfl((int)q32[2 * kk][0], srcA);
        unsigned aA1 = (unsigned)__shfl((int)q32[2 * kk + 1][0], srcA);
        unsigned bA0 = (unsigned)__shfl((int)q32[2 * kk][1], srcA);
        unsigned bA1 = (unsigned)__shfl((int)q32[2 * kk + 1][1], srcA);
        unsigned aB0 = (unsigned)__shfl((int)q32[2 * kk][0], srcB);
        unsigned aB1 = (unsigned)__shfl((int)q32[2 * kk + 1][0], srcB);
        unsigned bB0 = (unsigned)__shfl((int)q32[2 * kk][1], srcB);
        unsigned bB1 = (unsigned)__shfl((int)q32[2 * kk + 1][1], srcB);
        pa[kk].u[0] = hic ? aA1 : aA0;
        pa[kk].u[1] = hic ? bA1 : bA0;
        pa[kk].u[2] = hic ? aB1 : aB0;
        pa[kk].u[3] = hic ? bB1 : bB0;
      }
    }

    // ---- O^T += V^T·P^T ----
    __builtin_amdgcn_s_setprio(1);
    #pragma unroll
    for (int c = 0; c < 4; ++c) {
      short8 vf0 = *(const short8*)&Vs[buf][(c * 16 + lr) * 64 + ((lg) ^ (lr & 7)) * 8];
      short8 vf1 = *(const short8*)&Vs[buf][(c * 16 + lr) * 64 + ((4 + lg) ^ (lr & 7)) * 8];
      o[c] *= corr;
      o[c] = __builtin_amdgcn_mfma_f32_16x16x32_bf16(vf0, pa[0].s8, o[c], 0, 0, 0);
      o[c] = __builtin_amdgcn_mfma_f32_16x16x32_bf16(vf1, pa[1].s8, o[c], 0, 0, 0);
    }
    __builtin_amdgcn_s_setprio(0);

    if (pre) {
      #pragma unroll
      for (int i = 0; i < 2; ++i) {
        const int r = w * 16 + i * 8 + (l >> 3);
        const int sl = (l & 7) ^ (r & 7);
        *(short8*)&Ks[buf ^ 1][r * 64 + sl * 8] = sk[i];
        *(short8*)&Vs[buf ^ 1][r * 64 + sl * 8] = sv[i];
      }
    }
    buf ^= 1;
  }

  // epilogue: normalize (lane-local) + write y [B, T, C]; O^T frag: col q = lr,
  // row d = c*16 + lg*4 + j
  const int b = bh / H_, h = bh % H_;
  const float linv = 1.0f / ls;
  const size_t base = ((size_t)b * T_ + qrow) * C_ + h * 64;
  #pragma unroll
  for (int c = 0; c < 4; ++c) {
    ushort4 pk;
    pk.x = f2bf(o[c][0] * linv);
    pk.y = f2bf(o[c][1] * linv);
    pk.z = f2bf(o[c][2] * linv);
    pk.w = f2bf(o[c][3] * linv);
    *(ushort4*)(y + base + c * 16 + lg * 4) = pk;
  }
}

extern "C" void kernel_launch(void* const* d_in, const int* in_sizes, int n_in,
                              void* d_out, int out_size, void* d_ws, size_t ws_size,
                              hipStream_t stream) {
  const float* x  = (const float*)d_in[0];
  const float* Wq = (const float*)d_in[1];
  const float* bq = (const float*)d_in[2];
  const float* Wk = (const float*)d_in[3];
  const float* bk = (const float*)d_in[4];
  const float* Wv = (const float*)d_in[5];
  const float* bv = (const float*)d_in[6];
  const float* Wp = (const float*)d_in[7];
  const float* bp = (const float*)d_in[8];
  float* out = (float*)d_out;

  // ws: exact R3-proven footprint (~69 MB)
  char* p = (char*)d_ws;
  auto alloc = [&](size_t bytes) { char* r = p; p += (bytes + 255) & ~255ULL; return r; };
  ushort* xb  = (ushort*)alloc((size_t)BT_ * C_ * 2);
  ushort* wqb = (ushort*)alloc((size_t)C_ * C_ * 2);
  ushort* wkb = (ushort*)alloc((size_t)C_ * C_ * 2);
  ushort* wvb = (ushort*)alloc((size_t)C_ * C_ * 2);
  ushort* wpb = (ushort*)alloc((size_t)C_ * C_ * 2);
  ushort* qb  = (ushort*)alloc((size_t)BT_ * C_ * 2);
  ushort* kb  = (ushort*)alloc((size_t)BT_ * C_ * 2);
  ushort* vtb = (ushort*)alloc((size_t)BT_ * C_ * 2);   // V^T [B,H,64,T]
  ushort* yb  = (ushort*)alloc((size_t)BT_ * C_ * 2);
  float* ctab = (float*)alloc((size_t)T_ * 32 * 4);
  float* stab = (float*)alloc((size_t)T_ * 32 * 4);

  k_f32_to_bf16<<<(BT_ * C_ / 4 + 255) / 256, 256, 0, stream>>>(x, xb, BT_ * C_ / 4);
  k_f32_to_bf16<<<(C_ * C_ / 4 + 255) / 256, 256, 0, stream>>>(Wq, wqb, C_ * C_ / 4);
  k_f32_to_bf16<<<(C_ * C_ / 4 + 255) / 256, 256, 0, stream>>>(Wk, wkb, C_ * C_ / 4);
  k_f32_to_bf16<<<(C_ * C_ / 4 + 255) / 256, 256, 0, stream>>>(Wv, wvb, C_ * C_ / 4);
  k_f32_to_bf16<<<(C_ * C_ / 4 + 255) / 256, 256, 0, stream>>>(Wp, wpb, C_ * C_ / 4);
  k_rope_tab<<<T_ * 32 / 256, 256, 0, stream>>>(ctab, stab);

  k_qkv_gemm<<<dim3(BT_ / 128, 2304 / 128), 256, 0, stream>>>(
      xb, wqb, wkb, wvb, bq, bk, bv, qb, kb, vtb);

  // q: fold 1/sqrt(D) * log2(e) so attn softmax runs in exp2 domain
  k_rope_apply<<<(B_ * H_ * T_ * 32) / 256, 256, 0, stream>>>(qb, ctab, stab, 0.125f * 1.4426950408889634f);
  k_rope_apply<<<(B_ * H_ * T_ * 32) / 256, 256, 0, stream>>>(kb, ctab, stab, 1.0f);

  k_attn<<<dim3(1536), 256, 0, stream>>>(qb, kb, vtb, yb);

  k_proj_gemm<<<dim3(BT_ / 128, C_ / 128), 256, 0, stream>>>(yb, wpb, bp, out);
}

// Round 7
// 251.466 us; speedup vs baseline: 2.3794x; 1.0243x over previous
//
#include <hip/hip_runtime.h>
#include <hip/hip_bf16.h>

#define B_  2
#define T_  4096
#define C_  768
#define H_  12
#define D_  64
#define BT_ (B_*T_)   // 8192

typedef __attribute__((ext_vector_type(8))) short short8;
typedef __attribute__((ext_vector_type(4))) short short4b;
typedef __attribute__((ext_vector_type(4))) float f32x4;

union U32x2 { unsigned u[2]; short4b s4; };

__device__ __forceinline__ ushort f2bf(float f) {
  union { __hip_bfloat16 b; ushort u; } cv; cv.b = __float2bfloat16(f); return cv.u;
}
__device__ __forceinline__ float bf2f(ushort u) {
  unsigned x = ((unsigned)u) << 16; float f; __builtin_memcpy(&f, &x, 4); return f;
}
__device__ __forceinline__ unsigned pack2(float a, float b) {
  return (unsigned)f2bf(a) | ((unsigned)f2bf(b) << 16);
}

// 16x16x16 bf16 MFMA (K=16, A/B k-granule = lg*4+i) — builtin-name guarded.
__device__ __forceinline__ f32x4 mfma16(short4b a, short4b b, f32x4 c) {
#if __has_builtin(__builtin_amdgcn_mfma_f32_16x16x16bf16_1k)
  return __builtin_amdgcn_mfma_f32_16x16x16bf16_1k(a, b, c, 0, 0, 0);
#elif __has_builtin(__builtin_amdgcn_mfma_f32_16x16x16_bf16)
  return __builtin_amdgcn_mfma_f32_16x16x16_bf16(a, b, c, 0, 0, 0);
#else
  asm("v_mfma_f32_16x16x16_bf16 %0, %1, %2, %0" : "+v"(c) : "v"(a), "v"(b));
  return c;
#endif
}

// ---------------- elementwise converts ----------------
__global__ void k_f32_to_bf16(const float* __restrict__ in, ushort* __restrict__ out, int n4) {
  int i = blockIdx.x * blockDim.x + threadIdx.x;
  if (i >= n4) return;
  const float4 v = ((const float4*)in)[i];
  ushort4 o;
  o.x = f2bf(v.x); o.y = f2bf(v.y); o.z = f2bf(v.z); o.w = f2bf(v.w);
  ((ushort4*)out)[i] = o;
}

__global__ void k_rope_tab(float* __restrict__ ctab, float* __restrict__ stab) {
  int i = blockIdx.x * blockDim.x + threadIdx.x;  // T_*32 threads
  int t = i >> 5, p = i & 31;
  float inv = 1.0f / powf(10000.0f, (2.0f * (float)p) / 64.0f);
  float a = (float)t * inv;
  ctab[i] = cosf(a); stab[i] = sinf(a);
}

// in-place RoPE on [B*H, T, 64] bf16; q gets 1/8*log2(e) folded (exp2-domain softmax)
__global__ void k_rope_apply(ushort* __restrict__ x, const float* __restrict__ ctab,
                             const float* __restrict__ stab, float scale) {
  int i = blockIdx.x * blockDim.x + threadIdx.x;  // B_*H_*T_*32 threads
  int p = i & 31, t = (i >> 5) & (T_ - 1);
  size_t base = ((size_t)(i >> 5)) * 64 + (size_t)p * 2;
  uint xv = *(const uint*)(x + base);
  float x1 = bf2f((ushort)(xv & 0xffffu)), x2 = bf2f((ushort)(xv >> 16));
  float c = ctab[t * 32 + p], s = stab[t * 32 + p];
  float o1 = (x1 * c - x2 * s) * scale, o2 = (x1 * s + x2 * c) * scale;
  *(uint*)(x + base) = (uint)f2bf(o1) | ((uint)f2bf(o2) << 16);
}

// ---------------- QKV projection GEMM ----------------
// q,k -> [B,H,T,64]; v -> TRANSPOSED [B,H,64,T] (attn consumes V^T fragments).
__global__ __launch_bounds__(256) void k_qkv_gemm(
    const ushort* __restrict__ xb, const ushort* __restrict__ wq,
    const ushort* __restrict__ wk, const ushort* __restrict__ wv,
    const float* __restrict__ bq, const float* __restrict__ bk, const float* __restrict__ bv,
    ushort* __restrict__ qo, ushort* __restrict__ ko, ushort* __restrict__ vo) {
  __shared__ __align__(16) ushort As[128 * 72];
  __shared__ __align__(16) ushort Bs[128 * 72];
  const int tid = threadIdx.x, l = tid & 63, w = tid >> 6;
  const int lr = l & 15, lg = l >> 4;
  const int m0 = blockIdx.x * 128;
  const int n0g = blockIdx.y * 128;
  const int proj = n0g / 768;
  const int n0 = n0g % 768;
  const ushort* wsrc = proj == 0 ? wq : (proj == 1 ? wk : wv);
  const int wr = (w >> 1) * 64, wc = (w & 1) * 64;

  f32x4 acc[4][4];
  #pragma unroll
  for (int a = 0; a < 4; ++a)
    #pragma unroll
    for (int b = 0; b < 4; ++b) acc[a][b] = (f32x4){0.f, 0.f, 0.f, 0.f};

  for (int k0 = 0; k0 < 768; k0 += 64) {
    #pragma unroll
    for (int i = 0; i < 4; ++i) {
      int seg = tid + i * 256;
      int row = seg >> 3, c8 = (seg & 7) << 3;
      *(short8*)&As[row * 72 + c8] = *(const short8*)(xb + (size_t)(m0 + row) * 768 + k0 + c8);
      *(short8*)&Bs[row * 72 + c8] = *(const short8*)(wsrc + (size_t)(n0 + row) * 768 + k0 + c8);
    }
    __syncthreads();
    #pragma unroll
    for (int kk = 0; kk < 2; ++kk) {
      short8 af[4], bf[4];
      #pragma unroll
      for (int mi = 0; mi < 4; ++mi)
        af[mi] = *(const short8*)&As[(wr + mi * 16 + lr) * 72 + kk * 32 + lg * 8];
      #pragma unroll
      for (int ni = 0; ni < 4; ++ni)
        bf[ni] = *(const short8*)&Bs[(wc + ni * 16 + lr) * 72 + kk * 32 + lg * 8];
      #pragma unroll
      for (int mi = 0; mi < 4; ++mi)
        #pragma unroll
        for (int ni = 0; ni < 4; ++ni)
          acc[mi][ni] = __builtin_amdgcn_mfma_f32_16x16x32_bf16(af[mi], bf[ni], acc[mi][ni], 0, 0, 0);
    }
    __syncthreads();
  }

  const float* bias = proj == 0 ? bq : (proj == 1 ? bk : bv);
  if (proj == 2) {
    #pragma unroll
    for (int mi = 0; mi < 4; ++mi) {
      #pragma unroll
      for (int ni = 0; ni < 4; ++ni) {
        int colc = n0 + wc + ni * 16 + lr;
        float bb = bias[colc];
        int h = colc >> 6, d = colc & 63;
        int row0 = m0 + wr + mi * 16 + lg * 4;
        int b = row0 >> 12, t0 = row0 & (T_ - 1);
        ushort4 pk;
        pk.x = f2bf(acc[mi][ni][0] + bb);
        pk.y = f2bf(acc[mi][ni][1] + bb);
        pk.z = f2bf(acc[mi][ni][2] + bb);
        pk.w = f2bf(acc[mi][ni][3] + bb);
        *(ushort4*)(vo + (((size_t)b * H_ + h) * 64 + d) * T_ + t0) = pk;
      }
    }
  } else {
    ushort* dst = proj == 0 ? qo : ko;
    #pragma unroll
    for (int mi = 0; mi < 4; ++mi) {
      #pragma unroll
      for (int ni = 0; ni < 4; ++ni) {
        int colc = n0 + wc + ni * 16 + lr;
        float bb = bias[colc];
        int h = colc >> 6, d = colc & 63;
        #pragma unroll
        for (int j = 0; j < 4; ++j) {
          int row = m0 + wr + mi * 16 + lg * 4 + j;
          int b = row >> 12, t = row & (T_ - 1);
          dst[((((size_t)b * H_ + h) << 12) + t) * 64 + d] = f2bf(acc[mi][ni][j] + bb);
        }
      }
    }
  }
}

// ---------------- output projection GEMM (f32 out) ----------------
__global__ __launch_bounds__(256) void k_proj_gemm(
    const ushort* __restrict__ yb, const ushort* __restrict__ wp,
    const float* __restrict__ bp, float* __restrict__ out) {
  __shared__ __align__(16) ushort As[128 * 72];
  __shared__ __align__(16) ushort Bs[128 * 72];
  const int tid = threadIdx.x, l = tid & 63, w = tid >> 6;
  const int lr = l & 15, lg = l >> 4;
  const int m0 = blockIdx.x * 128;
  const int n0 = blockIdx.y * 128;
  const int wr = (w >> 1) * 64, wc = (w & 1) * 64;

  f32x4 acc[4][4];
  #pragma unroll
  for (int a = 0; a < 4; ++a)
    #pragma unroll
    for (int b = 0; b < 4; ++b) acc[a][b] = (f32x4){0.f, 0.f, 0.f, 0.f};

  for (int k0 = 0; k0 < 768; k0 += 64) {
    #pragma unroll
    for (int i = 0; i < 4; ++i) {
      int seg = tid + i * 256;
      int row = seg >> 3, c8 = (seg & 7) << 3;
      *(short8*)&As[row * 72 + c8] = *(const short8*)(yb + (size_t)(m0 + row) * 768 + k0 + c8);
      *(short8*)&Bs[row * 72 + c8] = *(const short8*)(wp + (size_t)(n0 + row) * 768 + k0 + c8);
    }
    __syncthreads();
    #pragma unroll
    for (int kk = 0; kk < 2; ++kk) {
      short8 af[4], bf[4];
      #pragma unroll
      for (int mi = 0; mi < 4; ++mi)
        af[mi] = *(const short8*)&As[(wr + mi * 16 + lr) * 72 + kk * 32 + lg * 8];
      #pragma unroll
      for (int ni = 0; ni < 4; ++ni)
        bf[ni] = *(const short8*)&Bs[(wc + ni * 16 + lr) * 72 + kk * 32 + lg * 8];
      #pragma unroll
      for (int mi = 0; mi < 4; ++mi)
        #pragma unroll
        for (int ni = 0; ni < 4; ++ni)
          acc[mi][ni] = __builtin_amdgcn_mfma_f32_16x16x32_bf16(af[mi], bf[ni], acc[mi][ni], 0, 0, 0);
    }
    __syncthreads();
  }

  #pragma unroll
  for (int mi = 0; mi < 4; ++mi)
    #pragma unroll
    for (int ni = 0; ni < 4; ++ni) {
      int col = n0 + wc + ni * 16 + lr;
      float bb = bp[col];
      #pragma unroll
      for (int j = 0; j < 4; ++j) {
        int row = m0 + wr + mi * 16 + lg * 4 + j;
        out[(size_t)row * 768 + col] = acc[mi][ni][j] + bb;
      }
    }
}

// ---------------- causal flash attention: one 64-row q-tile per block ----------
// grid 1536 1-D, balanced bid->(t,bh) mapping (R6-proven). O^T = V^T P^T.
// NEW vs R6: PV uses 16x16x16 MFMA whose B-frag k-granule (lg*4+i) exactly
// matches the S^T C-frag key-granule -> packed P feeds PV directly, the
// 16-bpermute exchange is deleted. V^T A-frags read as swizzled ds_read_b64.
// T13 defer-max (THR=8): skip O-rescale while per-tile max growth <= 8.
__global__ __launch_bounds__(256) void k_attn(
    const ushort* __restrict__ q, const ushort* __restrict__ k,
    const ushort* __restrict__ vt, ushort* __restrict__ y) {
  __shared__ __align__(16) ushort Ks[2][64 * 64];
  __shared__ __align__(16) ushort Vs[2][64 * 64];
  const int tid = threadIdx.x, l = tid & 63, w = tid >> 6;
  const int lr = l & 15, lg = l >> 4;
  const int bid = blockIdx.x;
  const int v = (bid & 255) * 6 + (bid >> 8);
  const int u = v & 63;
  const int t = (u & 1) ? 63 - (u >> 1) : (u >> 1);
  const int bh = v >> 6;
  const size_t kpl = (size_t)bh * T_ * 64;
  const size_t vpl = (size_t)bh * 64 * T_;
  const int qrow = t * 64 + w * 16 + lr;
  const int nt = t + 1;

  // Q fragments (B operand of S^T = K·Q: col=q=lane&15, k-rows = d)
  short8 qf[2];
  #pragma unroll
  for (int kk = 0; kk < 2; ++kk)
    qf[kk] = *(const short8*)(q + kpl + (size_t)qrow * 64 + kk * 32 + lg * 8);

  f32x4 o[4];
  float mx = -1e30f, ls = 0.f;
  #pragma unroll
  for (int c = 0; c < 4; ++c) o[c] = (f32x4){0.f, 0.f, 0.f, 0.f};

  // prologue: stage tile 0 into buf 0 (XOR-swizzled 16B slots)
  {
    #pragma unroll
    for (int i = 0; i < 2; ++i) {
      const int r = w * 16 + i * 8 + (l >> 3);
      const int sl = (l & 7) ^ (r & 7);
      short8 s0 = *(const short8*)(k + kpl + (size_t)r * 64 + (l & 7) * 8);
      short8 v0 = *(const short8*)(vt + vpl + (size_t)r * T_ + (l & 7) * 8);
      *(short8*)&Ks[0][r * 64 + sl * 8] = s0;
      *(short8*)&Vs[0][r * 64 + sl * 8] = v0;
    }
  }

  int buf = 0;
  for (int kt = 0; kt < nt; ++kt) {
    __syncthreads();
    // async-split staging: issue next tile's global loads before compute
    short8 sk[2], sv[2];
    const bool pre = (kt + 1 < nt);
    if (pre) {
      #pragma unroll
      for (int i = 0; i < 2; ++i) {
        const int r = w * 16 + i * 8 + (l >> 3);
        sk[i] = *(const short8*)(k + kpl + (size_t)((kt + 1) * 64 + r) * 64 + (l & 7) * 8);
        sv[i] = *(const short8*)(vt + vpl + (size_t)r * T_ + (kt + 1) * 64 + (l & 7) * 8);
      }
    }

    // ---- S^T = K·Q ----
    f32x4 sT[4];
    #pragma unroll
    for (int c = 0; c < 4; ++c) {
      short8 kf0 = *(const short8*)&Ks[buf][(c * 16 + lr) * 64 + ((lg) ^ (lr & 7)) * 8];
      short8 kf1 = *(const short8*)&Ks[buf][(c * 16 + lr) * 64 + ((4 + lg) ^ (lr & 7)) * 8];
      f32x4 z = (f32x4){0.f, 0.f, 0.f, 0.f};
      z = __builtin_amdgcn_mfma_f32_16x16x32_bf16(kf0, qf[0], z, 0, 0, 0);
      z = __builtin_amdgcn_mfma_f32_16x16x32_bf16(kf1, qf[1], z, 0, 0, 0);
      sT[c] = z;
    }

    // ---- softmax (lane-local state, q = lr) ----
    if (kt == t) {   // diagonal tile: causal mask (S^T row=key, col=q)
      #pragma unroll
      for (int c = 0; c < 4; ++c)
        #pragma unroll
        for (int j = 0; j < 4; ++j)
          if (kt * 64 + c * 16 + lg * 4 + j > qrow) sT[c][j] = -1e30f;
    }
    float vmax = sT[0][0];
    #pragma unroll
    for (int c = 0; c < 4; ++c)
      #pragma unroll
      for (int j = 0; j < 4; ++j) vmax = fmaxf(vmax, sT[c][j]);
    vmax = fmaxf(vmax, __shfl_xor(vmax, 16));
    vmax = fmaxf(vmax, __shfl_xor(vmax, 32));
    // T13 defer-max: only rescale when some row's max grew by more than THR=8
    if (__any(vmax > mx + 8.0f)) {
      const float mn = fmaxf(mx, vmax);
      const float corr = exp2f(mx - mn);
      mx = mn;
      ls *= corr;
      #pragma unroll
      for (int c = 0; c < 4; ++c) o[c] *= corr;
    }
    float rs = 0.f;
    U32x2 pb[4];
    #pragma unroll
    for (int c = 0; c < 4; ++c) {
      float p0 = exp2f(sT[c][0] - mx);
      float p1 = exp2f(sT[c][1] - mx);
      float p2 = exp2f(sT[c][2] - mx);
      float p3 = exp2f(sT[c][3] - mx);
      rs += (p0 + p1) + (p2 + p3);
      pb[c].u[0] = pack2(p0, p1); pb[c].u[1] = pack2(p2, p3);
    }
    rs += __shfl_xor(rs, 16);
    rs += __shfl_xor(rs, 32);
    ls += rs;

    // ---- O^T += V^T·P^T via 16x16x16 (P in-lane, no exchange) ----
    __builtin_amdgcn_s_setprio(1);
    #pragma unroll
    for (int ks = 0; ks < 4; ++ks) {
      #pragma unroll
      for (int c = 0; c < 4; ++c) {
        const int row = c * 16 + lr;
        const int sl = (2 * ks + (lg >> 1)) ^ (row & 7);
        short4b va = *(const short4b*)&Vs[buf][row * 64 + sl * 8 + (lg & 1) * 4];
        o[c] = mfma16(va, pb[ks].s4, o[c]);
      }
    }
    __builtin_amdgcn_s_setprio(0);

    if (pre) {
      #pragma unroll
      for (int i = 0; i < 2; ++i) {
        const int r = w * 16 + i * 8 + (l >> 3);
        const int sl = (l & 7) ^ (r & 7);
        *(short8*)&Ks[buf ^ 1][r * 64 + sl * 8] = sk[i];
        *(short8*)&Vs[buf ^ 1][r * 64 + sl * 8] = sv[i];
      }
    }
    buf ^= 1;
  }

  // epilogue: normalize (lane-local) + write y [B, T, C]; O^T frag: col q = lr,
  // row d = c*16 + lg*4 + j
  const int b = bh / H_, h = bh % H_;
  const float linv = 1.0f / ls;
  const size_t base = ((size_t)b * T_ + qrow) * C_ + h * 64;
  #pragma unroll
  for (int c = 0; c < 4; ++c) {
    ushort4 pk;
    pk.x = f2bf(o[c][0] * linv);
    pk.y = f2bf(o[c][1] * linv);
    pk.z = f2bf(o[c][2] * linv);
    pk.w = f2bf(o[c][3] * linv);
    *(ushort4*)(y + base + c * 16 + lg * 4) = pk;
  }
}

extern "C" void kernel_launch(void* const* d_in, const int* in_sizes, int n_in,
                              void* d_out, int out_size, void* d_ws, size_t ws_size,
                              hipStream_t stream) {
  const float* x  = (const float*)d_in[0];
  const float* Wq = (const float*)d_in[1];
  const float* bq = (const float*)d_in[2];
  const float* Wk = (const float*)d_in[3];
  const float* bk = (const float*)d_in[4];
  const float* Wv = (const float*)d_in[5];
  const float* bv = (const float*)d_in[6];
  const float* Wp = (const float*)d_in[7];
  const float* bp = (const float*)d_in[8];
  float* out = (float*)d_out;

  // ws: exact R3-proven footprint (~69 MB)
  char* p = (char*)d_ws;
  auto alloc = [&](size_t bytes) { char* r = p; p += (bytes + 255) & ~255ULL; return r; };
  ushort* xb  = (ushort*)alloc((size_t)BT_ * C_ * 2);
  ushort* wqb = (ushort*)alloc((size_t)C_ * C_ * 2);
  ushort* wkb = (ushort*)alloc((size_t)C_ * C_ * 2);
  ushort* wvb = (ushort*)alloc((size_t)C_ * C_ * 2);
  ushort* wpb = (ushort*)alloc((size_t)C_ * C_ * 2);
  ushort* qb  = (ushort*)alloc((size_t)BT_ * C_ * 2);
  ushort* kb  = (ushort*)alloc((size_t)BT_ * C_ * 2);
  ushort* vtb = (ushort*)alloc((size_t)BT_ * C_ * 2);   // V^T [B,H,64,T]
  ushort* yb  = (ushort*)alloc((size_t)BT_ * C_ * 2);
  float* ctab = (float*)alloc((size_t)T_ * 32 * 4);
  float* stab = (float*)alloc((size_t)T_ * 32 * 4);

  k_f32_to_bf16<<<(BT_ * C_ / 4 + 255) / 256, 256, 0, stream>>>(x, xb, BT_ * C_ / 4);
  k_f32_to_bf16<<<(C_ * C_ / 4 + 255) / 256, 256, 0, stream>>>(Wq, wqb, C_ * C_ / 4);
  k_f32_to_bf16<<<(C_ * C_ / 4 + 255) / 256, 256, 0, stream>>>(Wk, wkb, C_ * C_ / 4);
  k_f32_to_bf16<<<(C_ * C_ / 4 + 255) / 256, 256, 0, stream>>>(Wv, wvb, C_ * C_ / 4);
  k_f32_to_bf16<<<(C_ * C_ / 4 + 255) / 256, 256, 0, stream>>>(Wp, wpb, C_ * C_ / 4);
  k_rope_tab<<<T_ * 32 / 256, 256, 0, stream>>>(ctab, stab);

  k_qkv_gemm<<<dim3(BT_ / 128, 2304 / 128), 256, 0, stream>>>(
      xb, wqb, wkb, wvb, bq, bk, bv, qb, kb, vtb);

  // q: fold 1/sqrt(D) * log2(e) so attn softmax runs in exp2 domain
  k_rope_apply<<<(B_ * H_ * T_ * 32) / 256, 256, 0, stream>>>(qb, ctab, stab, 0.125f * 1.4426950408889634f);
  k_rope_apply<<<(B_ * H_ * T_ * 32) / 256, 256, 0, stream>>>(kb, ctab, stab, 1.0f);

  k_attn<<<dim3(1536), 256, 0, stream>>>(qb, kb, vtb, yb);

  k_proj_gemm<<<dim3(BT_ / 128, C_ / 128), 256, 0, stream>>>(yb, wpb, bp, out);
}

// Round 8
// 245.195 us; speedup vs baseline: 2.4403x; 1.0256x over previous
//
#include <hip/hip_runtime.h>
#include <hip/hip_bf16.h>

#define B_  2
#define T_  4096
#define C_  768
#define H_  12
#define D_  64
#define BT_ (B_*T_)   // 8192

typedef __attribute__((ext_vector_type(8))) short short8;
typedef __attribute__((ext_vector_type(4))) short short4b;
typedef __attribute__((ext_vector_type(4))) float f32x4;

union U32x2 { unsigned u[2]; short4b s4; };

__device__ __forceinline__ ushort f2bf(float f) {
  union { __hip_bfloat16 b; ushort u; } cv; cv.b = __float2bfloat16(f); return cv.u;
}
__device__ __forceinline__ float bf2f(ushort u) {
  unsigned x = ((unsigned)u) << 16; float f; __builtin_memcpy(&f, &x, 4); return f;
}
// compiler-friendly pack (lets clang fuse to v_cvt_pk_bf16_f32 — m240: do not hand-asm)
__device__ __forceinline__ unsigned pack2(float a, float b) {
  return (unsigned)f2bf(a) | ((unsigned)f2bf(b) << 16);
}

// 16x16x16 bf16 MFMA (K=16, A/B k-granule = lg*4+i) — builtin-name guarded.
__device__ __forceinline__ f32x4 mfma16(short4b a, short4b b, f32x4 c) {
#if __has_builtin(__builtin_amdgcn_mfma_f32_16x16x16bf16_1k)
  return __builtin_amdgcn_mfma_f32_16x16x16bf16_1k(a, b, c, 0, 0, 0);
#elif __has_builtin(__builtin_amdgcn_mfma_f32_16x16x16_bf16)
  return __builtin_amdgcn_mfma_f32_16x16x16_bf16(a, b, c, 0, 0, 0);
#else
  asm("v_mfma_f32_16x16x16_bf16 %0, %1, %2, %0" : "+v"(c) : "v"(a), "v"(b));
  return c;
#endif
}

// ---------------- elementwise converts ----------------
__global__ void k_f32_to_bf16(const float* __restrict__ in, ushort* __restrict__ out, int n4) {
  int i = blockIdx.x * blockDim.x + threadIdx.x;
  if (i >= n4) return;
  const float4 v = ((const float4*)in)[i];
  ushort4 o;
  o.x = f2bf(v.x); o.y = f2bf(v.y); o.z = f2bf(v.z); o.w = f2bf(v.w);
  ((ushort4*)out)[i] = o;
}

// all four weight matrices in one launch (blockIdx.y selects)
__global__ void k_w_to_bf16(const float* __restrict__ w0, const float* __restrict__ w1,
                            const float* __restrict__ w2, const float* __restrict__ w3,
                            ushort* __restrict__ o0, ushort* __restrict__ o1,
                            ushort* __restrict__ o2, ushort* __restrict__ o3, int n4) {
  int i = blockIdx.x * blockDim.x + threadIdx.x;
  if (i >= n4) return;
  const int sel = blockIdx.y;
  const float* in = sel == 0 ? w0 : (sel == 1 ? w1 : (sel == 2 ? w2 : w3));
  ushort* out = sel == 0 ? o0 : (sel == 1 ? o1 : (sel == 2 ? o2 : o3));
  const float4 v = ((const float4*)in)[i];
  ushort4 o;
  o.x = f2bf(v.x); o.y = f2bf(v.y); o.z = f2bf(v.z); o.w = f2bf(v.w);
  ((ushort4*)out)[i] = o;
}

__global__ void k_rope_tab(float* __restrict__ ctab, float* __restrict__ stab) {
  int i = blockIdx.x * blockDim.x + threadIdx.x;  // T_*32 threads
  int t = i >> 5, p = i & 31;
  float inv = 1.0f / powf(10000.0f, (2.0f * (float)p) / 64.0f);
  float a = (float)t * inv;
  ctab[i] = cosf(a); stab[i] = sinf(a);
}

// in-place RoPE on [B*H, T, 64] bf16; q gets 1/8*log2(e) folded (exp2-domain softmax)
__global__ void k_rope_apply(ushort* __restrict__ x, const float* __restrict__ ctab,
                             const float* __restrict__ stab, float scale) {
  int i = blockIdx.x * blockDim.x + threadIdx.x;  // B_*H_*T_*32 threads
  int p = i & 31, t = (i >> 5) & (T_ - 1);
  size_t base = ((size_t)(i >> 5)) * 64 + (size_t)p * 2;
  uint xv = *(const uint*)(x + base);
  float x1 = bf2f((ushort)(xv & 0xffffu)), x2 = bf2f((ushort)(xv >> 16));
  float c = ctab[t * 32 + p], s = stab[t * 32 + p];
  float o1 = (x1 * c - x2 * s) * scale, o2 = (x1 * s + x2 * c) * scale;
  *(uint*)(x + base) = (uint)f2bf(o1) | ((uint)f2bf(o2) << 16);
}

// ---------------- QKV projection GEMM ----------------
// q,k -> [B,H,T,64]; v -> TRANSPOSED [B,H,64,T] (attn consumes V^T fragments).
__global__ __launch_bounds__(256) void k_qkv_gemm(
    const ushort* __restrict__ xb, const ushort* __restrict__ wq,
    const ushort* __restrict__ wk, const ushort* __restrict__ wv,
    const float* __restrict__ bq, const float* __restrict__ bk, const float* __restrict__ bv,
    ushort* __restrict__ qo, ushort* __restrict__ ko, ushort* __restrict__ vo) {
  __shared__ __align__(16) ushort As[128 * 72];
  __shared__ __align__(16) ushort Bs[128 * 72];
  const int tid = threadIdx.x, l = tid & 63, w = tid >> 6;
  const int lr = l & 15, lg = l >> 4;
  const int m0 = blockIdx.x * 128;
  const int n0g = blockIdx.y * 128;
  const int proj = n0g / 768;
  const int n0 = n0g % 768;
  const ushort* wsrc = proj == 0 ? wq : (proj == 1 ? wk : wv);
  const int wr = (w >> 1) * 64, wc = (w & 1) * 64;

  f32x4 acc[4][4];
  #pragma unroll
  for (int a = 0; a < 4; ++a)
    #pragma unroll
    for (int b = 0; b < 4; ++b) acc[a][b] = (f32x4){0.f, 0.f, 0.f, 0.f};

  for (int k0 = 0; k0 < 768; k0 += 64) {
    #pragma unroll
    for (int i = 0; i < 4; ++i) {
      int seg = tid + i * 256;
      int row = seg >> 3, c8 = (seg & 7) << 3;
      *(short8*)&As[row * 72 + c8] = *(const short8*)(xb + (size_t)(m0 + row) * 768 + k0 + c8);
      *(short8*)&Bs[row * 72 + c8] = *(const short8*)(wsrc + (size_t)(n0 + row) * 768 + k0 + c8);
    }
    __syncthreads();
    #pragma unroll
    for (int kk = 0; kk < 2; ++kk) {
      short8 af[4], bf[4];
      #pragma unroll
      for (int mi = 0; mi < 4; ++mi)
        af[mi] = *(const short8*)&As[(wr + mi * 16 + lr) * 72 + kk * 32 + lg * 8];
      #pragma unroll
      for (int ni = 0; ni < 4; ++ni)
        bf[ni] = *(const short8*)&Bs[(wc + ni * 16 + lr) * 72 + kk * 32 + lg * 8];
      #pragma unroll
      for (int mi = 0; mi < 4; ++mi)
        #pragma unroll
        for (int ni = 0; ni < 4; ++ni)
          acc[mi][ni] = __builtin_amdgcn_mfma_f32_16x16x32_bf16(af[mi], bf[ni], acc[mi][ni], 0, 0, 0);
    }
    __syncthreads();
  }

  const float* bias = proj == 0 ? bq : (proj == 1 ? bk : bv);
  if (proj == 2) {
    #pragma unroll
    for (int mi = 0; mi < 4; ++mi) {
      #pragma unroll
      for (int ni = 0; ni < 4; ++ni) {
        int colc = n0 + wc + ni * 16 + lr;
        float bb = bias[colc];
        int h = colc >> 6, d = colc & 63;
        int row0 = m0 + wr + mi * 16 + lg * 4;
        int b = row0 >> 12, t0 = row0 & (T_ - 1);
        ushort4 pk;
        pk.x = f2bf(acc[mi][ni][0] + bb);
        pk.y = f2bf(acc[mi][ni][1] + bb);
        pk.z = f2bf(acc[mi][ni][2] + bb);
        pk.w = f2bf(acc[mi][ni][3] + bb);
        *(ushort4*)(vo + (((size_t)b * H_ + h) * 64 + d) * T_ + t0) = pk;
      }
    }
  } else {
    ushort* dst = proj == 0 ? qo : ko;
    #pragma unroll
    for (int mi = 0; mi < 4; ++mi) {
      #pragma unroll
      for (int ni = 0; ni < 4; ++ni) {
        int colc = n0 + wc + ni * 16 + lr;
        float bb = bias[colc];
        int h = colc >> 6, d = colc & 63;
        #pragma unroll
        for (int j = 0; j < 4; ++j) {
          int row = m0 + wr + mi * 16 + lg * 4 + j;
          int b = row >> 12, t = row & (T_ - 1);
          dst[((((size_t)b * H_ + h) << 12) + t) * 64 + d] = f2bf(acc[mi][ni][j] + bb);
        }
      }
    }
  }
}

// ---------------- output projection GEMM (f32 out) ----------------
__global__ __launch_bounds__(256) void k_proj_gemm(
    const ushort* __restrict__ yb, const ushort* __restrict__ wp,
    const float* __restrict__ bp, float* __restrict__ out) {
  __shared__ __align__(16) ushort As[128 * 72];
  __shared__ __align__(16) ushort Bs[128 * 72];
  const int tid = threadIdx.x, l = tid & 63, w = tid >> 6;
  const int lr = l & 15, lg = l >> 4;
  const int m0 = blockIdx.x * 128;
  const int n0 = blockIdx.y * 128;
  const int wr = (w >> 1) * 64, wc = (w & 1) * 64;

  f32x4 acc[4][4];
  #pragma unroll
  for (int a = 0; a < 4; ++a)
    #pragma unroll
    for (int b = 0; b < 4; ++b) acc[a][b] = (f32x4){0.f, 0.f, 0.f, 0.f};

  for (int k0 = 0; k0 < 768; k0 += 64) {
    #pragma unroll
    for (int i = 0; i < 4; ++i) {
      int seg = tid + i * 256;
      int row = seg >> 3, c8 = (seg & 7) << 3;
      *(short8*)&As[row * 72 + c8] = *(const short8*)(yb + (size_t)(m0 + row) * 768 + k0 + c8);
      *(short8*)&Bs[row * 72 + c8] = *(const short8*)(wp + (size_t)(n0 + row) * 768 + k0 + c8);
    }
    __syncthreads();
    #pragma unroll
    for (int kk = 0; kk < 2; ++kk) {
      short8 af[4], bf[4];
      #pragma unroll
      for (int mi = 0; mi < 4; ++mi)
        af[mi] = *(const short8*)&As[(wr + mi * 16 + lr) * 72 + kk * 32 + lg * 8];
      #pragma unroll
      for (int ni = 0; ni < 4; ++ni)
        bf[ni] = *(const short8*)&Bs[(wc + ni * 16 + lr) * 72 + kk * 32 + lg * 8];
      #pragma unroll
      for (int mi = 0; mi < 4; ++mi)
        #pragma unroll
        for (int ni = 0; ni < 4; ++ni)
          acc[mi][ni] = __builtin_amdgcn_mfma_f32_16x16x32_bf16(af[mi], bf[ni], acc[mi][ni], 0, 0, 0);
    }
    __syncthreads();
  }

  #pragma unroll
  for (int mi = 0; mi < 4; ++mi)
    #pragma unroll
    for (int ni = 0; ni < 4; ++ni) {
      int col = n0 + wc + ni * 16 + lr;
      float bb = bp[col];
      #pragma unroll
      for (int j = 0; j < 4; ++j) {
        int row = m0 + wr + mi * 16 + lg * 4 + j;
        out[(size_t)row * 768 + col] = acc[mi][ni][j] + bb;
      }
    }
}

// ---------------- causal flash attention: one 64-row q-tile per block ----------
// grid 1536 1-D, balanced bid->(t,bh) mapping (R6-proven). O^T = V^T P^T.
// PV via 16x16x16 MFMA (P in-lane, no exchange). T13 defer-max THR=8.
// NEW vs R7: -mx folded into QK C-init (common path has NO per-element sub),
// mx init 0 (softmax shift-invariance; f32-safe), max3-fusable vmax chains,
// compiler-friendly bf16 pack.
__global__ __launch_bounds__(256) void k_attn(
    const ushort* __restrict__ q, const ushort* __restrict__ k,
    const ushort* __restrict__ vt, ushort* __restrict__ y) {
  __shared__ __align__(16) ushort Ks[2][64 * 64];
  __shared__ __align__(16) ushort Vs[2][64 * 64];
  const int tid = threadIdx.x, l = tid & 63, w = tid >> 6;
  const int lr = l & 15, lg = l >> 4;
  const int bid = blockIdx.x;
  const int v = (bid & 255) * 6 + (bid >> 8);
  const int u = v & 63;
  const int t = (u & 1) ? 63 - (u >> 1) : (u >> 1);
  const int bh = v >> 6;
  const size_t kpl = (size_t)bh * T_ * 64;
  const size_t vpl = (size_t)bh * 64 * T_;
  const int qrow = t * 64 + w * 16 + lr;
  const int nt = t + 1;

  // Q fragments (B operand of S^T = K·Q: col=q=lane&15, k-rows = d)
  short8 qf[2];
  #pragma unroll
  for (int kk = 0; kk < 2; ++kk)
    qf[kk] = *(const short8*)(q + kpl + (size_t)qrow * 64 + kk * 32 + lg * 8);

  f32x4 o[4];
  float mx = 0.0f, ls = 0.f;   // mx=0 init: shift-invariant, keeps C-fold f32-exact
  #pragma unroll
  for (int c = 0; c < 4; ++c) o[c] = (f32x4){0.f, 0.f, 0.f, 0.f};

  // prologue: stage tile 0 into buf 0 (XOR-swizzled 16B slots)
  {
    #pragma unroll
    for (int i = 0; i < 2; ++i) {
      const int r = w * 16 + i * 8 + (l >> 3);
      const int sl = (l & 7) ^ (r & 7);
      short8 s0 = *(const short8*)(k + kpl + (size_t)r * 64 + (l & 7) * 8);
      short8 v0 = *(const short8*)(vt + vpl + (size_t)r * T_ + (l & 7) * 8);
      *(short8*)&Ks[0][r * 64 + sl * 8] = s0;
      *(short8*)&Vs[0][r * 64 + sl * 8] = v0;
    }
  }

  int buf = 0;
  for (int kt = 0; kt < nt; ++kt) {
    __syncthreads();
    // async-split staging: issue next tile's global loads before compute
    short8 sk[2], sv[2];
    const bool pre = (kt + 1 < nt);
    if (pre) {
      #pragma unroll
      for (int i = 0; i < 2; ++i) {
        const int r = w * 16 + i * 8 + (l >> 3);
        sk[i] = *(const short8*)(k + kpl + (size_t)((kt + 1) * 64 + r) * 64 + (l & 7) * 8);
        sv[i] = *(const short8*)(vt + vpl + (size_t)r * T_ + (kt + 1) * 64 + (l & 7) * 8);
      }
    }

    // ---- S^T = K·Q - mx (shift folded into MFMA C-init) ----
    const f32x4 zinit = (f32x4){-mx, -mx, -mx, -mx};
    f32x4 sT[4];
    #pragma unroll
    for (int c = 0; c < 4; ++c) {
      short8 kf0 = *(const short8*)&Ks[buf][(c * 16 + lr) * 64 + ((lg) ^ (lr & 7)) * 8];
      short8 kf1 = *(const short8*)&Ks[buf][(c * 16 + lr) * 64 + ((4 + lg) ^ (lr & 7)) * 8];
      f32x4 z = zinit;
      z = __builtin_amdgcn_mfma_f32_16x16x32_bf16(kf0, qf[0], z, 0, 0, 0);
      z = __builtin_amdgcn_mfma_f32_16x16x32_bf16(kf1, qf[1], z, 0, 0, 0);
      sT[c] = z;
    }

    // ---- softmax (lane-local state, q = lr); sT is RELATIVE to mx ----
    if (kt == t) {   // diagonal tile: causal mask (S^T row=key, col=q)
      #pragma unroll
      for (int c = 0; c < 4; ++c)
        #pragma unroll
        for (int j = 0; j < 4; ++j)
          if (kt * 64 + c * 16 + lg * 4 + j > qrow) sT[c][j] = -1e30f;
    }
    // max3-fusable chains: ((a max b) max c) max d per c, then chain across c
    float cm0 = fmaxf(fmaxf(fmaxf(sT[0][0], sT[0][1]), sT[0][2]), sT[0][3]);
    float cm1 = fmaxf(fmaxf(fmaxf(sT[1][0], sT[1][1]), sT[1][2]), sT[1][3]);
    float cm2 = fmaxf(fmaxf(fmaxf(sT[2][0], sT[2][1]), sT[2][2]), sT[2][3]);
    float cm3 = fmaxf(fmaxf(fmaxf(sT[3][0], sT[3][1]), sT[3][2]), sT[3][3]);
    float vmax = fmaxf(fmaxf(fmaxf(cm0, cm1), cm2), cm3);
    vmax = fmaxf(vmax, __shfl_xor(vmax, 16));
    vmax = fmaxf(vmax, __shfl_xor(vmax, 32));
    // T13 defer-max: rescale only when relative growth exceeds THR=8
    if (__any(vmax > 8.0f)) {
      const float g = fmaxf(vmax, 0.0f);
      const float corr = exp2f(-g);
      mx += g;
      ls *= corr;
      #pragma unroll
      for (int c = 0; c < 4; ++c) o[c] *= corr;
      #pragma unroll
      for (int c = 0; c < 4; ++c)
        #pragma unroll
        for (int j = 0; j < 4; ++j) sT[c][j] -= g;
    }
    // common path: p = exp2(sT) directly — no subtraction
    float rs = 0.f;
    U32x2 pb[4];
    #pragma unroll
    for (int c = 0; c < 4; ++c) {
      float p0 = exp2f(sT[c][0]);
      float p1 = exp2f(sT[c][1]);
      float p2 = exp2f(sT[c][2]);
      float p3 = exp2f(sT[c][3]);
      rs += (p0 + p1) + (p2 + p3);
      pb[c].u[0] = pack2(p0, p1); pb[c].u[1] = pack2(p2, p3);
    }
    rs += __shfl_xor(rs, 16);
    rs += __shfl_xor(rs, 32);
    ls += rs;

    // ---- O^T += V^T·P^T via 16x16x16 (P in-lane, no exchange) ----
    __builtin_amdgcn_s_setprio(1);
    #pragma unroll
    for (int ks = 0; ks < 4; ++ks) {
      #pragma unroll
      for (int c = 0; c < 4; ++c) {
        const int row = c * 16 + lr;
        const int sl = (2 * ks + (lg >> 1)) ^ (row & 7);
        short4b va = *(const short4b*)&Vs[buf][row * 64 + sl * 8 + (lg & 1) * 4];
        o[c] = mfma16(va, pb[ks].s4, o[c]);
      }
    }
    __builtin_amdgcn_s_setprio(0);

    if (pre) {
      #pragma unroll
      for (int i = 0; i < 2; ++i) {
        const int r = w * 16 + i * 8 + (l >> 3);
        const int sl = (l & 7) ^ (r & 7);
        *(short8*)&Ks[buf ^ 1][r * 64 + sl * 8] = sk[i];
        *(short8*)&Vs[buf ^ 1][r * 64 + sl * 8] = sv[i];
      }
    }
    buf ^= 1;
  }

  // epilogue: normalize (lane-local) + write y [B, T, C]; O^T frag: col q = lr,
  // row d = c*16 + lg*4 + j
  const int b = bh / H_, h = bh % H_;
  const float linv = 1.0f / ls;
  const size_t base = ((size_t)b * T_ + qrow) * C_ + h * 64;
  #pragma unroll
  for (int c = 0; c < 4; ++c) {
    ushort4 pk;
    pk.x = f2bf(o[c][0] * linv);
    pk.y = f2bf(o[c][1] * linv);
    pk.z = f2bf(o[c][2] * linv);
    pk.w = f2bf(o[c][3] * linv);
    *(ushort4*)(y + base + c * 16 + lg * 4) = pk;
  }
}

extern "C" void kernel_launch(void* const* d_in, const int* in_sizes, int n_in,
                              void* d_out, int out_size, void* d_ws, size_t ws_size,
                              hipStream_t stream) {
  const float* x  = (const float*)d_in[0];
  const float* Wq = (const float*)d_in[1];
  const float* bq = (const float*)d_in[2];
  const float* Wk = (const float*)d_in[3];
  const float* bk = (const float*)d_in[4];
  const float* Wv = (const float*)d_in[5];
  const float* bv = (const float*)d_in[6];
  const float* Wp = (const float*)d_in[7];
  const float* bp = (const float*)d_in[8];
  float* out = (float*)d_out;

  // ws: exact R3-proven footprint (~69 MB)
  char* p = (char*)d_ws;
  auto alloc = [&](size_t bytes) { char* r = p; p += (bytes + 255) & ~255ULL; return r; };
  ushort* xb  = (ushort*)alloc((size_t)BT_ * C_ * 2);
  ushort* wqb = (ushort*)alloc((size_t)C_ * C_ * 2);
  ushort* wkb = (ushort*)alloc((size_t)C_ * C_ * 2);
  ushort* wvb = (ushort*)alloc((size_t)C_ * C_ * 2);
  ushort* wpb = (ushort*)alloc((size_t)C_ * C_ * 2);
  ushort* qb  = (ushort*)alloc((size_t)BT_ * C_ * 2);
  ushort* kb  = (ushort*)alloc((size_t)BT_ * C_ * 2);
  ushort* vtb = (ushort*)alloc((size_t)BT_ * C_ * 2);   // V^T [B,H,64,T]
  ushort* yb  = (ushort*)alloc((size_t)BT_ * C_ * 2);
  float* ctab = (float*)alloc((size_t)T_ * 32 * 4);
  float* stab = (float*)alloc((size_t)T_ * 32 * 4);

  k_f32_to_bf16<<<(BT_ * C_ / 4 + 255) / 256, 256, 0, stream>>>(x, xb, BT_ * C_ / 4);
  k_w_to_bf16<<<dim3((C_ * C_ / 4 + 255) / 256, 4), 256, 0, stream>>>(
      Wq, Wk, Wv, Wp, wqb, wkb, wvb, wpb, C_ * C_ / 4);
  k_rope_tab<<<T_ * 32 / 256, 256, 0, stream>>>(ctab, stab);

  k_qkv_gemm<<<dim3(BT_ / 128, 2304 / 128), 256, 0, stream>>>(
      xb, wqb, wkb, wvb, bq, bk, bv, qb, kb, vtb);

  // q: fold 1/sqrt(D) * log2(e) so attn softmax runs in exp2 domain
  k_rope_apply<<<(B_ * H_ * T_ * 32) / 256, 256, 0, stream>>>(qb, ctab, stab, 0.125f * 1.4426950408889634f);
  k_rope_apply<<<(B_ * H_ * T_ * 32) / 256, 256, 0, stream>>>(kb, ctab, stab, 1.0f);

  k_attn<<<dim3(1536), 256, 0, stream>>>(qb, kb, vtb, yb);

  k_proj_gemm<<<dim3(BT_ / 128, C_ / 128), 256, 0, stream>>>(yb, wpb, bp, out);
}

// Round 9
// 244.814 us; speedup vs baseline: 2.4441x; 1.0016x over previous
//
#include <hip/hip_runtime.h>
#include <hip/hip_bf16.h>

#define B_  2
#define T_  4096
#define C_  768
#define H_  12
#define D_  64
#define BT_ (B_*T_)   // 8192

typedef __attribute__((ext_vector_type(8))) short short8;
typedef __attribute__((ext_vector_type(4))) short short4b;
typedef __attribute__((ext_vector_type(4))) float f32x4;

union U32x2 { unsigned u[2]; short4b s4; };

__device__ __forceinline__ ushort f2bf(float f) {
  union { __hip_bfloat16 b; ushort u; } cv; cv.b = __float2bfloat16(f); return cv.u;
}
__device__ __forceinline__ float bf2f(ushort u) {
  unsigned x = ((unsigned)u) << 16; float f; __builtin_memcpy(&f, &x, 4); return f;
}
// compiler-friendly pack (clang fuses to v_cvt_pk_bf16_f32)
__device__ __forceinline__ unsigned pack2(float a, float b) {
  return (unsigned)f2bf(a) | ((unsigned)f2bf(b) << 16);
}

// 16x16x16 bf16 MFMA (K=16, A/B k-granule = lg*4+i) — builtin-name guarded.
__device__ __forceinline__ f32x4 mfma16(short4b a, short4b b, f32x4 c) {
#if __has_builtin(__builtin_amdgcn_mfma_f32_16x16x16bf16_1k)
  return __builtin_amdgcn_mfma_f32_16x16x16bf16_1k(a, b, c, 0, 0, 0);
#elif __has_builtin(__builtin_amdgcn_mfma_f32_16x16x16_bf16)
  return __builtin_amdgcn_mfma_f32_16x16x16_bf16(a, b, c, 0, 0, 0);
#else
  asm("v_mfma_f32_16x16x16_bf16 %0, %1, %2, %0" : "+v"(c) : "v"(a), "v"(b));
  return c;
#endif
}

// ---------------- elementwise converts ----------------
__global__ void k_f32_to_bf16(const float* __restrict__ in, ushort* __restrict__ out, int n4) {
  int i = blockIdx.x * blockDim.x + threadIdx.x;
  if (i >= n4) return;
  const float4 v = ((const float4*)in)[i];
  ushort4 o;
  o.x = f2bf(v.x); o.y = f2bf(v.y); o.z = f2bf(v.z); o.w = f2bf(v.w);
  ((ushort4*)out)[i] = o;
}

// all four weight matrices in one launch (blockIdx.y selects)
__global__ void k_w_to_bf16(const float* __restrict__ w0, const float* __restrict__ w1,
                            const float* __restrict__ w2, const float* __restrict__ w3,
                            ushort* __restrict__ o0, ushort* __restrict__ o1,
                            ushort* __restrict__ o2, ushort* __restrict__ o3, int n4) {
  int i = blockIdx.x * blockDim.x + threadIdx.x;
  if (i >= n4) return;
  const int sel = blockIdx.y;
  const float* in = sel == 0 ? w0 : (sel == 1 ? w1 : (sel == 2 ? w2 : w3));
  ushort* out = sel == 0 ? o0 : (sel == 1 ? o1 : (sel == 2 ? o2 : o3));
  const float4 v = ((const float4*)in)[i];
  ushort4 o;
  o.x = f2bf(v.x); o.y = f2bf(v.y); o.z = f2bf(v.z); o.w = f2bf(v.w);
  ((ushort4*)out)[i] = o;
}

__global__ void k_rope_tab(float* __restrict__ ctab, float* __restrict__ stab) {
  int i = blockIdx.x * blockDim.x + threadIdx.x;  // T_*32 threads
  int t = i >> 5, p = i & 31;
  float inv = 1.0f / powf(10000.0f, (2.0f * (float)p) / 64.0f);
  float a = (float)t * inv;
  ctab[i] = cosf(a); stab[i] = sinf(a);
}

// fused in-place RoPE on q and k [B*H, T, 64] bf16 (blockIdx.y: 0=q, 1=k);
// q gets 1/8*log2(e) folded (exp2-domain softmax)
__global__ void k_rope_qk(ushort* __restrict__ qx, ushort* __restrict__ kx,
                          const float* __restrict__ ctab, const float* __restrict__ stab) {
  int i = blockIdx.x * blockDim.x + threadIdx.x;  // B_*H_*T_*32 threads
  ushort* x = blockIdx.y ? kx : qx;
  const float scale = blockIdx.y ? 1.0f : 0.125f * 1.4426950408889634f;
  int p = i & 31, t = (i >> 5) & (T_ - 1);
  size_t base = ((size_t)(i >> 5)) * 64 + (size_t)p * 2;
  uint xv = *(const uint*)(x + base);
  float x1 = bf2f((ushort)(xv & 0xffffu)), x2 = bf2f((ushort)(xv >> 16));
  float c = ctab[t * 32 + p], s = stab[t * 32 + p];
  float o1 = (x1 * c - x2 * s) * scale, o2 = (x1 * s + x2 * c) * scale;
  *(uint*)(x + base) = (uint)f2bf(o1) | ((uint)f2bf(o2) << 16);
}

// ---------------- QKV projection GEMM ----------------
// q,k -> [B,H,T,64]; v -> TRANSPOSED [B,H,64,T] (attn consumes V^T fragments).
__global__ __launch_bounds__(256) void k_qkv_gemm(
    const ushort* __restrict__ xb, const ushort* __restrict__ wq,
    const ushort* __restrict__ wk, const ushort* __restrict__ wv,
    const float* __restrict__ bq, const float* __restrict__ bk, const float* __restrict__ bv,
    ushort* __restrict__ qo, ushort* __restrict__ ko, ushort* __restrict__ vo) {
  __shared__ __align__(16) ushort As[128 * 72];
  __shared__ __align__(16) ushort Bs[128 * 72];
  const int tid = threadIdx.x, l = tid & 63, w = tid >> 6;
  const int lr = l & 15, lg = l >> 4;
  const int m0 = blockIdx.x * 128;
  const int n0g = blockIdx.y * 128;
  const int proj = n0g / 768;
  const int n0 = n0g % 768;
  const ushort* wsrc = proj == 0 ? wq : (proj == 1 ? wk : wv);
  const int wr = (w >> 1) * 64, wc = (w & 1) * 64;

  f32x4 acc[4][4];
  #pragma unroll
  for (int a = 0; a < 4; ++a)
    #pragma unroll
    for (int b = 0; b < 4; ++b) acc[a][b] = (f32x4){0.f, 0.f, 0.f, 0.f};

  for (int k0 = 0; k0 < 768; k0 += 64) {
    #pragma unroll
    for (int i = 0; i < 4; ++i) {
      int seg = tid + i * 256;
      int row = seg >> 3, c8 = (seg & 7) << 3;
      *(short8*)&As[row * 72 + c8] = *(const short8*)(xb + (size_t)(m0 + row) * 768 + k0 + c8);
      *(short8*)&Bs[row * 72 + c8] = *(const short8*)(wsrc + (size_t)(n0 + row) * 768 + k0 + c8);
    }
    __syncthreads();
    #pragma unroll
    for (int kk = 0; kk < 2; ++kk) {
      short8 af[4], bf[4];
      #pragma unroll
      for (int mi = 0; mi < 4; ++mi)
        af[mi] = *(const short8*)&As[(wr + mi * 16 + lr) * 72 + kk * 32 + lg * 8];
      #pragma unroll
      for (int ni = 0; ni < 4; ++ni)
        bf[ni] = *(const short8*)&Bs[(wc + ni * 16 + lr) * 72 + kk * 32 + lg * 8];
      #pragma unroll
      for (int mi = 0; mi < 4; ++mi)
        #pragma unroll
        for (int ni = 0; ni < 4; ++ni)
          acc[mi][ni] = __builtin_amdgcn_mfma_f32_16x16x32_bf16(af[mi], bf[ni], acc[mi][ni], 0, 0, 0);
    }
    __syncthreads();
  }

  const float* bias = proj == 0 ? bq : (proj == 1 ? bk : bv);
  if (proj == 2) {
    #pragma unroll
    for (int mi = 0; mi < 4; ++mi) {
      #pragma unroll
      for (int ni = 0; ni < 4; ++ni) {
        int colc = n0 + wc + ni * 16 + lr;
        float bb = bias[colc];
        int h = colc >> 6, d = colc & 63;
        int row0 = m0 + wr + mi * 16 + lg * 4;
        int b = row0 >> 12, t0 = row0 & (T_ - 1);
        ushort4 pk;
        pk.x = f2bf(acc[mi][ni][0] + bb);
        pk.y = f2bf(acc[mi][ni][1] + bb);
        pk.z = f2bf(acc[mi][ni][2] + bb);
        pk.w = f2bf(acc[mi][ni][3] + bb);
        *(ushort4*)(vo + (((size_t)b * H_ + h) * 64 + d) * T_ + t0) = pk;
      }
    }
  } else {
    ushort* dst = proj == 0 ? qo : ko;
    #pragma unroll
    for (int mi = 0; mi < 4; ++mi) {
      #pragma unroll
      for (int ni = 0; ni < 4; ++ni) {
        int colc = n0 + wc + ni * 16 + lr;
        float bb = bias[colc];
        int h = colc >> 6, d = colc & 63;
        #pragma unroll
        for (int j = 0; j < 4; ++j) {
          int row = m0 + wr + mi * 16 + lg * 4 + j;
          int b = row >> 12, t = row & (T_ - 1);
          dst[((((size_t)b * H_ + h) << 12) + t) * 64 + d] = f2bf(acc[mi][ni][j] + bb);
        }
      }
    }
  }
}

// ---------------- output projection GEMM (f32 out) ----------------
__global__ __launch_bounds__(256) void k_proj_gemm(
    const ushort* __restrict__ yb, const ushort* __restrict__ wp,
    const float* __restrict__ bp, float* __restrict__ out) {
  __shared__ __align__(16) ushort As[128 * 72];
  __shared__ __align__(16) ushort Bs[128 * 72];
  const int tid = threadIdx.x, l = tid & 63, w = tid >> 6;
  const int lr = l & 15, lg = l >> 4;
  const int m0 = blockIdx.x * 128;
  const int n0 = blockIdx.y * 128;
  const int wr = (w >> 1) * 64, wc = (w & 1) * 64;

  f32x4 acc[4][4];
  #pragma unroll
  for (int a = 0; a < 4; ++a)
    #pragma unroll
    for (int b = 0; b < 4; ++b) acc[a][b] = (f32x4){0.f, 0.f, 0.f, 0.f};

  for (int k0 = 0; k0 < 768; k0 += 64) {
    #pragma unroll
    for (int i = 0; i < 4; ++i) {
      int seg = tid + i * 256;
      int row = seg >> 3, c8 = (seg & 7) << 3;
      *(short8*)&As[row * 72 + c8] = *(const short8*)(yb + (size_t)(m0 + row) * 768 + k0 + c8);
      *(short8*)&Bs[row * 72 + c8] = *(const short8*)(wp + (size_t)(n0 + row) * 768 + k0 + c8);
    }
    __syncthreads();
    #pragma unroll
    for (int kk = 0; kk < 2; ++kk) {
      short8 af[4], bf[4];
      #pragma unroll
      for (int mi = 0; mi < 4; ++mi)
        af[mi] = *(const short8*)&As[(wr + mi * 16 + lr) * 72 + kk * 32 + lg * 8];
      #pragma unroll
      for (int ni = 0; ni < 4; ++ni)
        bf[ni] = *(const short8*)&Bs[(wc + ni * 16 + lr) * 72 + kk * 32 + lg * 8];
      #pragma unroll
      for (int mi = 0; mi < 4; ++mi)
        #pragma unroll
        for (int ni = 0; ni < 4; ++ni)
          acc[mi][ni] = __builtin_amdgcn_mfma_f32_16x16x32_bf16(af[mi], bf[ni], acc[mi][ni], 0, 0, 0);
    }
    __syncthreads();
  }

  #pragma unroll
  for (int mi = 0; mi < 4; ++mi)
    #pragma unroll
    for (int ni = 0; ni < 4; ++ni) {
      int col = n0 + wc + ni * 16 + lr;
      float bb = bp[col];
      #pragma unroll
      for (int j = 0; j < 4; ++j) {
        int row = m0 + wr + mi * 16 + lg * 4 + j;
        out[(size_t)row * 768 + col] = acc[mi][ni][j] + bb;
      }
    }
}

// ---------------- causal flash attention: one 64-row q-tile per block ----------
// grid 1536 1-D, balanced bid->(t,bh) mapping (R6-proven). O^T = V^T P^T.
// PV via 16x16x16 MFMA (P in-lane). T13 defer-max THR=8, -mx folded into C-init.
// NEW vs R8: LDS 32->24KB (K double-buffered, V SINGLE-buffered with a second
// barrier after PV) -> 6 blocks/CU co-resident (was 5 + tail).
__global__ __launch_bounds__(256) void k_attn(
    const ushort* __restrict__ q, const ushort* __restrict__ k,
    const ushort* __restrict__ vt, ushort* __restrict__ y) {
  __shared__ __align__(16) ushort Ks[2][64 * 64];
  __shared__ __align__(16) ushort Vs[64 * 64];
  const int tid = threadIdx.x, l = tid & 63, w = tid >> 6;
  const int lr = l & 15, lg = l >> 4;
  const int bid = blockIdx.x;
  const int v = (bid & 255) * 6 + (bid >> 8);
  const int u = v & 63;
  const int t = (u & 1) ? 63 - (u >> 1) : (u >> 1);
  const int bh = v >> 6;
  const size_t kpl = (size_t)bh * T_ * 64;
  const size_t vpl = (size_t)bh * 64 * T_;
  const int qrow = t * 64 + w * 16 + lr;
  const int nt = t + 1;

  // Q fragments (B operand of S^T = K·Q: col=q=lane&15, k-rows = d)
  short8 qf[2];
  #pragma unroll
  for (int kk = 0; kk < 2; ++kk)
    qf[kk] = *(const short8*)(q + kpl + (size_t)qrow * 64 + kk * 32 + lg * 8);

  f32x4 o[4];
  float mx = 0.0f, ls = 0.f;   // mx=0 init: shift-invariant, keeps C-fold f32-exact
  #pragma unroll
  for (int c = 0; c < 4; ++c) o[c] = (f32x4){0.f, 0.f, 0.f, 0.f};

  // prologue: stage tile 0 (XOR-swizzled 16B slots)
  {
    #pragma unroll
    for (int i = 0; i < 2; ++i) {
      const int r = w * 16 + i * 8 + (l >> 3);
      const int sl = (l & 7) ^ (r & 7);
      short8 s0 = *(const short8*)(k + kpl + (size_t)r * 64 + (l & 7) * 8);
      short8 v0 = *(const short8*)(vt + vpl + (size_t)r * T_ + (l & 7) * 8);
      *(short8*)&Ks[0][r * 64 + sl * 8] = s0;
      *(short8*)&Vs[r * 64 + sl * 8] = v0;
    }
  }

  int buf = 0;
  for (int kt = 0; kt < nt; ++kt) {
    __syncthreads();   // (A) staged K[buf]/V visible
    // async-split staging: issue next tile's global loads before compute
    short8 sk[2], sv[2];
    const bool pre = (kt + 1 < nt);
    if (pre) {
      #pragma unroll
      for (int i = 0; i < 2; ++i) {
        const int r = w * 16 + i * 8 + (l >> 3);
        sk[i] = *(const short8*)(k + kpl + (size_t)((kt + 1) * 64 + r) * 64 + (l & 7) * 8);
        sv[i] = *(const short8*)(vt + vpl + (size_t)r * T_ + (kt + 1) * 64 + (l & 7) * 8);
      }
    }

    // ---- S^T = K·Q - mx (shift folded into MFMA C-init) ----
    const f32x4 zinit = (f32x4){-mx, -mx, -mx, -mx};
    f32x4 sT[4];
    #pragma unroll
    for (int c = 0; c < 4; ++c) {
      short8 kf0 = *(const short8*)&Ks[buf][(c * 16 + lr) * 64 + ((lg) ^ (lr & 7)) * 8];
      short8 kf1 = *(const short8*)&Ks[buf][(c * 16 + lr) * 64 + ((4 + lg) ^ (lr & 7)) * 8];
      f32x4 z = zinit;
      z = __builtin_amdgcn_mfma_f32_16x16x32_bf16(kf0, qf[0], z, 0, 0, 0);
      z = __builtin_amdgcn_mfma_f32_16x16x32_bf16(kf1, qf[1], z, 0, 0, 0);
      sT[c] = z;
    }

    // ---- softmax (lane-local state, q = lr); sT is RELATIVE to mx ----
    if (kt == t) {   // diagonal tile: causal mask (S^T row=key, col=q)
      #pragma unroll
      for (int c = 0; c < 4; ++c)
        #pragma unroll
        for (int j = 0; j < 4; ++j)
          if (kt * 64 + c * 16 + lg * 4 + j > qrow) sT[c][j] = -1e30f;
    }
    float cm0 = fmaxf(fmaxf(fmaxf(sT[0][0], sT[0][1]), sT[0][2]), sT[0][3]);
    float cm1 = fmaxf(fmaxf(fmaxf(sT[1][0], sT[1][1]), sT[1][2]), sT[1][3]);
    float cm2 = fmaxf(fmaxf(fmaxf(sT[2][0], sT[2][1]), sT[2][2]), sT[2][3]);
    float cm3 = fmaxf(fmaxf(fmaxf(sT[3][0], sT[3][1]), sT[3][2]), sT[3][3]);
    float vmax = fmaxf(fmaxf(fmaxf(cm0, cm1), cm2), cm3);
    vmax = fmaxf(vmax, __shfl_xor(vmax, 16));
    vmax = fmaxf(vmax, __shfl_xor(vmax, 32));
    // T13 defer-max: rescale only when relative growth exceeds THR=8
    if (__any(vmax > 8.0f)) {
      const float g = fmaxf(vmax, 0.0f);
      const float corr = exp2f(-g);
      mx += g;
      ls *= corr;
      #pragma unroll
      for (int c = 0; c < 4; ++c) o[c] *= corr;
      #pragma unroll
      for (int c = 0; c < 4; ++c)
        #pragma unroll
        for (int j = 0; j < 4; ++j) sT[c][j] -= g;
    }
    // common path: p = exp2(sT) directly — no subtraction
    float rs = 0.f;
    U32x2 pb[4];
    #pragma unroll
    for (int c = 0; c < 4; ++c) {
      float p0 = exp2f(sT[c][0]);
      float p1 = exp2f(sT[c][1]);
      float p2 = exp2f(sT[c][2]);
      float p3 = exp2f(sT[c][3]);
      rs += (p0 + p1) + (p2 + p3);
      pb[c].u[0] = pack2(p0, p1); pb[c].u[1] = pack2(p2, p3);
    }
    rs += __shfl_xor(rs, 16);
    rs += __shfl_xor(rs, 32);
    ls += rs;

    // ---- O^T += V^T·P^T via 16x16x16 (P in-lane, no exchange) ----
    __builtin_amdgcn_s_setprio(1);
    #pragma unroll
    for (int ks = 0; ks < 4; ++ks) {
      #pragma unroll
      for (int c = 0; c < 4; ++c) {
        const int row = c * 16 + lr;
        const int sl = (2 * ks + (lg >> 1)) ^ (row & 7);
        short4b va = *(const short4b*)&Vs[row * 64 + sl * 8 + (lg & 1) * 4];
        o[c] = mfma16(va, pb[ks].s4, o[c]);
      }
    }
    __builtin_amdgcn_s_setprio(0);

    __syncthreads();   // (B) all waves done reading Vs before overwrite
    if (pre) {
      #pragma unroll
      for (int i = 0; i < 2; ++i) {
        const int r = w * 16 + i * 8 + (l >> 3);
        const int sl = (l & 7) ^ (r & 7);
        *(short8*)&Ks[buf ^ 1][r * 64 + sl * 8] = sk[i];
        *(short8*)&Vs[r * 64 + sl * 8] = sv[i];
      }
    }
    buf ^= 1;
  }

  // epilogue: normalize (lane-local) + write y [B, T, C]; O^T frag: col q = lr,
  // row d = c*16 + lg*4 + j
  const int b = bh / H_, h = bh % H_;
  const float linv = 1.0f / ls;
  const size_t base = ((size_t)b * T_ + qrow) * C_ + h * 64;
  #pragma unroll
  for (int c = 0; c < 4; ++c) {
    ushort4 pk;
    pk.x = f2bf(o[c][0] * linv);
    pk.y = f2bf(o[c][1] * linv);
    pk.z = f2bf(o[c][2] * linv);
    pk.w = f2bf(o[c][3] * linv);
    *(ushort4*)(y + base + c * 16 + lg * 4) = pk;
  }
}

extern "C" void kernel_launch(void* const* d_in, const int* in_sizes, int n_in,
                              void* d_out, int out_size, void* d_ws, size_t ws_size,
                              hipStream_t stream) {
  const float* x  = (const float*)d_in[0];
  const float* Wq = (const float*)d_in[1];
  const float* bq = (const float*)d_in[2];
  const float* Wk = (const float*)d_in[3];
  const float* bk = (const float*)d_in[4];
  const float* Wv = (const float*)d_in[5];
  const float* bv = (const float*)d_in[6];
  const float* Wp = (const float*)d_in[7];
  const float* bp = (const float*)d_in[8];
  float* out = (float*)d_out;

  // ws: exact R3-proven footprint (~69 MB)
  char* p = (char*)d_ws;
  auto alloc = [&](size_t bytes) { char* r = p; p += (bytes + 255) & ~255ULL; return r; };
  ushort* xb  = (ushort*)alloc((size_t)BT_ * C_ * 2);
  ushort* wqb = (ushort*)alloc((size_t)C_ * C_ * 2);
  ushort* wkb = (ushort*)alloc((size_t)C_ * C_ * 2);
  ushort* wvb = (ushort*)alloc((size_t)C_ * C_ * 2);
  ushort* wpb = (ushort*)alloc((size_t)C_ * C_ * 2);
  ushort* qb  = (ushort*)alloc((size_t)BT_ * C_ * 2);
  ushort* kb  = (ushort*)alloc((size_t)BT_ * C_ * 2);
  ushort* vtb = (ushort*)alloc((size_t)BT_ * C_ * 2);   // V^T [B,H,64,T]
  ushort* yb  = (ushort*)alloc((size_t)BT_ * C_ * 2);
  float* ctab = (float*)alloc((size_t)T_ * 32 * 4);
  float* stab = (float*)alloc((size_t)T_ * 32 * 4);

  k_f32_to_bf16<<<(BT_ * C_ / 4 + 255) / 256, 256, 0, stream>>>(x, xb, BT_ * C_ / 4);
  k_w_to_bf16<<<dim3((C_ * C_ / 4 + 255) / 256, 4), 256, 0, stream>>>(
      Wq, Wk, Wv, Wp, wqb, wkb, wvb, wpb, C_ * C_ / 4);
  k_rope_tab<<<T_ * 32 / 256, 256, 0, stream>>>(ctab, stab);

  k_qkv_gemm<<<dim3(BT_ / 128, 2304 / 128), 256, 0, stream>>>(
      xb, wqb, wkb, wvb, bq, bk, bv, qb, kb, vtb);

  // fused RoPE on q (scale = log2(e)/8 folded) and k
  k_rope_qk<<<dim3((B_ * H_ * T_ * 32) / 256, 2), 256, 0, stream>>>(qb, kb, ctab, stab);

  k_attn<<<dim3(1536), 256, 0, stream>>>(qb, kb, vtb, yb);

  k_proj_gemm<<<dim3(BT_ / 128, C_ / 128), 256, 0, stream>>>(yb, wpb, bp, out);
}